// Round 1
// baseline (541.096 us; speedup 1.0000x reference)
//
#include <hip/hip_runtime.h>

// ---------- types ----------
typedef __attribute__((ext_vector_type(4))) float  f32x4;
typedef __attribute__((ext_vector_type(4))) float  float4v;
typedef __attribute__((ext_vector_type(8))) short  s16x8;   // 8 bf16 (4 VGPRs)
typedef __attribute__((ext_vector_type(8))) unsigned short u16x8;

static __device__ __forceinline__ unsigned short f2bf(float f) {
    unsigned int u = __builtin_bit_cast(unsigned int, f);
    u += 0x7fffu + ((u >> 16) & 1u);      // round-to-nearest-even
    return (unsigned short)(u >> 16);
}

// =====================================================================
// NT GEMM: out[M,N] = A[M,K] * W[N,K]^T   (M=8192, N=1024, K=1024)
// MODE 0: A=fp32 q,  out = Qh bf16 [B,H,L,64]  (scaled by 1/8)
// MODE 1: A=fp32 k,  out = Kh bf16 [B,H,L,64]
// MODE 2: A=fp32 v,  out = Vt bf16 [B,H,64,L]  (transposed)
// MODE 3: A=bf16 ctx,out = fp32 [B,L,D]
// =====================================================================
template<int MODE>
__global__ __launch_bounds__(256)
void proj_kernel(const void* __restrict__ Ain, const float* __restrict__ W,
                 void* __restrict__ Out)
{
    __shared__ unsigned short Asw[128 * 64];   // swizzled bf16 tile
    __shared__ unsigned short Bsw[128 * 64];

    const int tid  = threadIdx.x;
    const int lane = tid & 63;
    const int wave = tid >> 6;
    const int wr   = wave >> 1, wc = wave & 1;
    const int g    = lane >> 4, l16 = lane & 15;
    const int bx   = blockIdx.x & 7;    // N tile (8)
    const int by   = blockIdx.x >> 3;   // M tile (64)

    f32x4 acc[4][4] = {};

    for (int kt = 0; kt < 16; ++kt) {
        __syncthreads();
        #pragma unroll
        for (int j = 0; j < 4; ++j) {
            const int ch  = tid + j * 256;
            const int r   = ch >> 3, c = ch & 7;
            const int off = (r * 128 + c * 16) ^ ((r & 7) << 4);
            // ---- A tile ----
            if (MODE == 3) {
                const unsigned short* ap = (const unsigned short*)Ain
                    + (size_t)(by * 128 + r) * 1024 + kt * 64 + c * 8;
                *(u16x8*)((char*)Asw + off) = *(const u16x8*)ap;
            } else {
                const float* ap = (const float*)Ain
                    + (size_t)(by * 128 + r) * 1024 + kt * 64 + c * 8;
                float4v f0 = *(const float4v*)ap;
                float4v f1 = *(const float4v*)(ap + 4);
                u16x8 w;
                #pragma unroll
                for (int i = 0; i < 4; ++i) { w[i] = f2bf(f0[i]); w[i + 4] = f2bf(f1[i]); }
                *(u16x8*)((char*)Asw + off) = w;
            }
            // ---- B tile (W is always fp32) ----
            const float* bp = W + (size_t)(bx * 128 + r) * 1024 + kt * 64 + c * 8;
            float4v b0 = *(const float4v*)bp;
            float4v b1 = *(const float4v*)(bp + 4);
            u16x8 wb;
            #pragma unroll
            for (int i = 0; i < 4; ++i) { wb[i] = f2bf(b0[i]); wb[i + 4] = f2bf(b1[i]); }
            *(u16x8*)((char*)Bsw + off) = wb;
        }
        __syncthreads();

        #pragma unroll
        for (int ks = 0; ks < 2; ++ks) {
            s16x8 af[4], bf[4];
            #pragma unroll
            for (int mi = 0; mi < 4; ++mi) {
                const int row = wr * 64 + mi * 16 + l16;
                const int off = (row * 128 + g * 16 + ks * 64) ^ ((row & 7) << 4);
                af[mi] = __builtin_bit_cast(s16x8, *(const u16x8*)((const char*)Asw + off));
            }
            #pragma unroll
            for (int ni = 0; ni < 4; ++ni) {
                const int row = wc * 64 + ni * 16 + l16;
                const int off = (row * 128 + g * 16 + ks * 64) ^ ((row & 7) << 4);
                bf[ni] = __builtin_bit_cast(s16x8, *(const u16x8*)((const char*)Bsw + off));
            }
            #pragma unroll
            for (int mi = 0; mi < 4; ++mi)
                #pragma unroll
                for (int ni = 0; ni < 4; ++ni)
                    acc[mi][ni] = __builtin_amdgcn_mfma_f32_16x16x32_bf16(
                        af[mi], bf[ni], acc[mi][ni], 0, 0, 0);
        }
    }

    // ---- epilogue ----
    #pragma unroll
    for (int mi = 0; mi < 4; ++mi) {
        #pragma unroll
        for (int ni = 0; ni < 4; ++ni) {
            #pragma unroll
            for (int rr = 0; rr < 4; ++rr) {
                const int gr = by * 128 + wr * 64 + mi * 16 + g * 4 + rr; // M index
                const int gc = bx * 128 + wc * 64 + ni * 16 + l16;        // N index
                float v = acc[mi][ni][rr];
                if (MODE == 0 || MODE == 1) {
                    const int b = gr >> 11, ll = gr & 2047, h = gc >> 6, dh = gc & 63;
                    if (MODE == 0) v *= 0.125f;  // 1/sqrt(DH)
                    ((unsigned short*)Out)[(size_t)((b * 16 + h) * 2048 + ll) * 64 + dh] = f2bf(v);
                } else if (MODE == 2) {
                    const int b = gr >> 11, ll = gr & 2047, h = gc >> 6, dh = gc & 63;
                    ((unsigned short*)Out)[(size_t)((b * 16 + h) * 64 + dh) * 2048 + ll] = f2bf(v);
                } else {
                    ((float*)Out)[(size_t)gr * 1024 + gc] = v;
                }
            }
        }
    }
}

// =====================================================================
// Flash-style causal attention.
// Qh,Kh: [B,H,L,64] bf16 (Q pre-scaled by 1/8); Vt: [B,H,64,L] bf16
// Ctx out: [B,L,D] bf16
// Block = 256 thr (4 waves), handles 64 q rows of one (b,h); wave w owns 16.
// =====================================================================
__global__ __launch_bounds__(256)
void attn_kernel(const unsigned short* __restrict__ Qh,
                 const unsigned short* __restrict__ Kh,
                 const unsigned short* __restrict__ Vt,
                 unsigned short* __restrict__ Ctx)
{
    __shared__ unsigned short Ksw[64 * 64];      // [kv][d] swizzled
    __shared__ unsigned short Vsw[64 * 64];      // [d][kv] swizzled
    __shared__ unsigned short Psw[4][16 * 64];   // per-wave [q][kv] swizzled

    const int tid  = threadIdx.x;
    const int lane = tid & 63;
    const int wave = tid >> 6;
    const int g    = lane >> 4, l16 = lane & 15;
    const int bh   = blockIdx.x >> 5;   // b*16+h
    const int qb   = blockIdx.x & 31;   // q tile of 64
    const int b    = bh >> 4, h = bh & 15;

    // Q fragments in registers (A-frag: row=l16, k = g*8 + ks*32 + e)
    s16x8 qf[2];
    {
        const unsigned short* qp = Qh + ((size_t)bh * 2048 + qb * 64 + wave * 16 + l16) * 64 + g * 8;
        qf[0] = __builtin_bit_cast(s16x8, *(const u16x8*)qp);
        qf[1] = __builtin_bit_cast(s16x8, *(const u16x8*)(qp + 32));
    }

    f32x4 o[4] = {};
    float m[4], l[4];
    #pragma unroll
    for (int rr = 0; rr < 4; ++rr) { m[rr] = -3.0e38f; l[rr] = 0.f; }

    for (int t = 0; t <= qb; ++t) {
        const int kv0 = t * 64;
        __syncthreads();
        #pragma unroll
        for (int j = 0; j < 2; ++j) {
            const int ch  = tid + j * 256;
            const int r   = ch >> 3, c = ch & 7;
            const int off = (r * 128 + c * 16) ^ ((r & 7) << 4);
            const unsigned short* kp = Kh + ((size_t)bh * 2048 + kv0 + r) * 64 + c * 8;
            *(u16x8*)((char*)Ksw + off) = *(const u16x8*)kp;
            const unsigned short* vp = Vt + ((size_t)bh * 64 + r) * 2048 + kv0 + c * 8;
            *(u16x8*)((char*)Vsw + off) = *(const u16x8*)vp;
        }
        __syncthreads();

        // ---- S = Q K^T (rows q, cols kv) ----
        f32x4 s[4] = {};
        #pragma unroll
        for (int nt = 0; nt < 4; ++nt) {
            #pragma unroll
            for (int ks = 0; ks < 2; ++ks) {
                const int row = nt * 16 + l16;
                const int off = (row * 128 + g * 16 + ks * 64) ^ ((row & 7) << 4);
                s16x8 kf = __builtin_bit_cast(s16x8, *(const u16x8*)((const char*)Ksw + off));
                s[nt] = __builtin_amdgcn_mfma_f32_16x16x32_bf16(qf[ks], kf, s[nt], 0, 0, 0);
            }
        }

        // ---- causal mask on diagonal tile ----
        if (t == qb) {
            #pragma unroll
            for (int nt = 0; nt < 4; ++nt)
                #pragma unroll
                for (int rr = 0; rr < 4; ++rr) {
                    const int kv_g = kv0 + nt * 16 + l16;
                    const int q_g  = qb * 64 + wave * 16 + g * 4 + rr;
                    if (kv_g > q_g) s[nt][rr] = -3.0e38f;
                }
        }

        // ---- online softmax (rows live on (g,rr); reduce over 16-lane group) ----
        float sc[4];
        #pragma unroll
        for (int rr = 0; rr < 4; ++rr) {
            float tmax = fmaxf(fmaxf(s[0][rr], s[1][rr]), fmaxf(s[2][rr], s[3][rr]));
            tmax = fmaxf(tmax, __shfl_xor(tmax, 1));
            tmax = fmaxf(tmax, __shfl_xor(tmax, 2));
            tmax = fmaxf(tmax, __shfl_xor(tmax, 4));
            tmax = fmaxf(tmax, __shfl_xor(tmax, 8));
            const float mn = fmaxf(m[rr], tmax);
            sc[rr] = __expf(m[rr] - mn);
            m[rr]  = mn;
            float r0 = 0.f;
            #pragma unroll
            for (int nt = 0; nt < 4; ++nt) {
                const float p = __expf(s[nt][rr] - mn);
                s[nt][rr] = p;
                r0 += p;
            }
            r0 += __shfl_xor(r0, 1);
            r0 += __shfl_xor(r0, 2);
            r0 += __shfl_xor(r0, 4);
            r0 += __shfl_xor(r0, 8);
            l[rr] = l[rr] * sc[rr] + r0;
        }
        #pragma unroll
        for (int nt = 0; nt < 4; ++nt)
            #pragma unroll
            for (int rr = 0; rr < 4; ++rr)
                o[nt][rr] *= sc[rr];

        // ---- P -> per-wave LDS (bf16), then PV ----
        unsigned short* Pw = Psw[wave];
        #pragma unroll
        for (int nt = 0; nt < 4; ++nt)
            #pragma unroll
            for (int rr = 0; rr < 4; ++rr) {
                const int qr  = g * 4 + rr;
                const int off = (qr * 128 + (nt * 16 + l16) * 2) ^ ((qr & 7) << 4);
                *(unsigned short*)((char*)Pw + off) = f2bf(s[nt][rr]);
            }
        // wave-private LDS: no barrier needed (in-order per-wave DS pipe)

        #pragma unroll
        for (int ks = 0; ks < 2; ++ks) {
            const int offp = (l16 * 128 + g * 16 + ks * 64) ^ ((l16 & 7) << 4);
            s16x8 pf = __builtin_bit_cast(s16x8, *(const u16x8*)((const char*)Pw + offp));
            #pragma unroll
            for (int nt = 0; nt < 4; ++nt) {
                const int row = nt * 16 + l16;
                const int off = (row * 128 + g * 16 + ks * 64) ^ ((row & 7) << 4);
                s16x8 vf = __builtin_bit_cast(s16x8, *(const u16x8*)((const char*)Vsw + off));
                o[nt] = __builtin_amdgcn_mfma_f32_16x16x32_bf16(pf, vf, o[nt], 0, 0, 0);
            }
        }
    }

    // ---- epilogue: ctx[b, q, h*64+d] = o / l ----
    #pragma unroll
    for (int rr = 0; rr < 4; ++rr) {
        const float inv = 1.0f / l[rr];
        const int q_g = qb * 64 + wave * 16 + g * 4 + rr;
        #pragma unroll
        for (int nt = 0; nt < 4; ++nt) {
            const int d = nt * 16 + l16;
            Ctx[((size_t)b * 2048 + q_g) * 1024 + h * 64 + d] = f2bf(o[nt][rr] * inv);
        }
    }
}

// =====================================================================
extern "C" void kernel_launch(void* const* d_in, const int* in_sizes, int n_in,
                              void* d_out, int out_size, void* d_ws, size_t ws_size,
                              hipStream_t stream)
{
    const float* q  = (const float*)d_in[0];
    const float* k  = (const float*)d_in[1];
    const float* v  = (const float*)d_in[2];
    // d_in[3] = mask (causal tril, known statically) — unused
    const float* Wq = (const float*)d_in[4];
    const float* Wk = (const float*)d_in[5];
    const float* Wv = (const float*)d_in[6];
    const float* Wo = (const float*)d_in[7];

    const size_t NE = (size_t)4 * 16 * 2048 * 64;     // 8,388,608 elems per tensor
    unsigned short* Qh  = (unsigned short*)d_ws;
    unsigned short* Kh  = Qh + NE;
    unsigned short* Vt  = Kh + NE;
    unsigned short* Ctx = Vt + NE;

    dim3 blk(256);
    proj_kernel<0><<<dim3(512), blk, 0, stream>>>(q, Wq, Qh);
    proj_kernel<1><<<dim3(512), blk, 0, stream>>>(k, Wk, Kh);
    proj_kernel<2><<<dim3(512), blk, 0, stream>>>(v, Wv, Vt);
    attn_kernel   <<<dim3(2048), blk, 0, stream>>>(Qh, Kh, Vt, Ctx);
    proj_kernel<3><<<dim3(512), blk, 0, stream>>>(Ctx, Wo, (float*)d_out);
}

// Round 2
// 328.581 us; speedup vs baseline: 1.6468x; 1.6468x over previous
//
#include <hip/hip_runtime.h>

// ---------- types ----------
typedef __attribute__((ext_vector_type(4))) float  f32x4;
typedef __attribute__((ext_vector_type(4))) float  float4v;
typedef __attribute__((ext_vector_type(8))) short  s16x8;   // 8 bf16 (4 VGPRs)
typedef __attribute__((ext_vector_type(8))) unsigned short u16x8;

static __device__ __forceinline__ unsigned short f2bf(float f) {
    unsigned int u = __builtin_bit_cast(unsigned int, f);
    u += 0x7fffu + ((u >> 16) & 1u);      // round-to-nearest-even
    return (unsigned short)(u >> 16);
}

// =====================================================================
// NT GEMM: out[M,N] = A[M,K] * W[N,K]^T   (M=8192, N=1024, K=1024)
// MODE 0: A=fp32 q,  out = Qh bf16 [B,H,L,64]  (scaled by 1/8)
// MODE 1: A=fp32 k,  out = Kh bf16 [B,H,L,64]
// MODE 2: A=fp32 v,  out = Vt bf16 [B,H,64,L]  (transposed)
// MODE 3: A=bf16 ctx,out = fp32 [B,L,D]
// =====================================================================
template<int MODE>
__global__ __launch_bounds__(256)
void proj_kernel(const void* __restrict__ Ain, const float* __restrict__ W,
                 void* __restrict__ Out)
{
    __shared__ unsigned short Asw[128 * 64];   // swizzled bf16 tile
    __shared__ unsigned short Bsw[128 * 64];

    const int tid  = threadIdx.x;
    const int lane = tid & 63;
    const int wave = tid >> 6;
    const int wr   = wave >> 1, wc = wave & 1;
    const int g    = lane >> 4, l16 = lane & 15;
    const int bx   = blockIdx.x & 7;    // N tile (8)
    const int by   = blockIdx.x >> 3;   // M tile (64)

    f32x4 acc[4][4] = {};

    for (int kt = 0; kt < 16; ++kt) {
        __syncthreads();
        #pragma unroll
        for (int j = 0; j < 4; ++j) {
            const int ch  = tid + j * 256;
            const int r   = ch >> 3, c = ch & 7;
            const int off = (r * 128 + c * 16) ^ ((r & 7) << 4);
            // ---- A tile ----
            if (MODE == 3) {
                const unsigned short* ap = (const unsigned short*)Ain
                    + (size_t)(by * 128 + r) * 1024 + kt * 64 + c * 8;
                *(u16x8*)((char*)Asw + off) = *(const u16x8*)ap;
            } else {
                const float* ap = (const float*)Ain
                    + (size_t)(by * 128 + r) * 1024 + kt * 64 + c * 8;
                float4v f0 = *(const float4v*)ap;
                float4v f1 = *(const float4v*)(ap + 4);
                u16x8 w;
                #pragma unroll
                for (int i = 0; i < 4; ++i) { w[i] = f2bf(f0[i]); w[i + 4] = f2bf(f1[i]); }
                *(u16x8*)((char*)Asw + off) = w;
            }
            // ---- B tile (W is always fp32) ----
            const float* bp = W + (size_t)(bx * 128 + r) * 1024 + kt * 64 + c * 8;
            float4v b0 = *(const float4v*)bp;
            float4v b1 = *(const float4v*)(bp + 4);
            u16x8 wb;
            #pragma unroll
            for (int i = 0; i < 4; ++i) { wb[i] = f2bf(b0[i]); wb[i + 4] = f2bf(b1[i]); }
            *(u16x8*)((char*)Bsw + off) = wb;
        }
        __syncthreads();

        #pragma unroll
        for (int ks = 0; ks < 2; ++ks) {
            s16x8 af[4], bf[4];
            #pragma unroll
            for (int mi = 0; mi < 4; ++mi) {
                const int row = wr * 64 + mi * 16 + l16;
                const int off = (row * 128 + g * 16 + ks * 64) ^ ((row & 7) << 4);
                af[mi] = __builtin_bit_cast(s16x8, *(const u16x8*)((const char*)Asw + off));
            }
            #pragma unroll
            for (int ni = 0; ni < 4; ++ni) {
                const int row = wc * 64 + ni * 16 + l16;
                const int off = (row * 128 + g * 16 + ks * 64) ^ ((row & 7) << 4);
                bf[ni] = __builtin_bit_cast(s16x8, *(const u16x8*)((const char*)Bsw + off));
            }
            #pragma unroll
            for (int mi = 0; mi < 4; ++mi)
                #pragma unroll
                for (int ni = 0; ni < 4; ++ni)
                    acc[mi][ni] = __builtin_amdgcn_mfma_f32_16x16x32_bf16(
                        af[mi], bf[ni], acc[mi][ni], 0, 0, 0);
        }
    }

    // ---- epilogue ----
    #pragma unroll
    for (int mi = 0; mi < 4; ++mi) {
        #pragma unroll
        for (int ni = 0; ni < 4; ++ni) {
            #pragma unroll
            for (int rr = 0; rr < 4; ++rr) {
                const int gr = by * 128 + wr * 64 + mi * 16 + g * 4 + rr; // M index
                const int gc = bx * 128 + wc * 64 + ni * 16 + l16;        // N index
                float v = acc[mi][ni][rr];
                if (MODE == 0 || MODE == 1) {
                    const int b = gr >> 11, ll = gr & 2047, h = gc >> 6, dh = gc & 63;
                    if (MODE == 0) v *= 0.125f;  // 1/sqrt(DH)
                    ((unsigned short*)Out)[(size_t)((b * 16 + h) * 2048 + ll) * 64 + dh] = f2bf(v);
                } else if (MODE == 2) {
                    const int b = gr >> 11, ll = gr & 2047, h = gc >> 6, dh = gc & 63;
                    ((unsigned short*)Out)[(size_t)((b * 16 + h) * 64 + dh) * 2048 + ll] = f2bf(v);
                } else {
                    ((float*)Out)[(size_t)gr * 1024 + gc] = v;
                }
            }
        }
    }
}

// =====================================================================
// Flash-style causal attention, double-buffered KV.
// Qh,Kh: [B,H,L,64] bf16 (Q pre-scaled by 1/8); Vt: [B,H,64,L] bf16
// Ctx out: [B,L,D] bf16
// Block = 512 thr (8 waves) owns 128 q rows of one (b,h); wave w owns 16.
// Grid = 16 qtiles (reversed: big first) x 64 bh = 1024 blocks.
// =====================================================================
__global__ __launch_bounds__(512)
void attn_kernel(const unsigned short* __restrict__ Qh,
                 const unsigned short* __restrict__ Kh,
                 const unsigned short* __restrict__ Vt,
                 unsigned short* __restrict__ Ctx)
{
    __shared__ unsigned short Ksw[2][64 * 64];   // [kv][d] swizzled, dbuf
    __shared__ unsigned short Vsw[2][64 * 64];   // [d][kv] swizzled, dbuf
    __shared__ unsigned short Psw[8][16 * 64];   // per-wave [q][kv] swizzled

    const int tid  = threadIdx.x;
    const int lane = tid & 63;
    const int wave = tid >> 6;
    const int g    = lane >> 4, l16 = lane & 15;
    const int qb   = 15 - (int)(blockIdx.x >> 6);  // big q-tiles dispatched first
    const int bh   = blockIdx.x & 63;
    const int b    = bh >> 4, h = bh & 15;
    const int qrow0 = qb * 128 + wave * 16;        // wave's first q row
    const int ntile = 2 * qb + 2;                  // kv tiles of 64

    // staging mapping: 512 threads cover a 64x64 bf16 tile, 8 elems each
    const int sr = tid >> 3, sc = tid & 7;
    const int soff = (sr * 128 + sc * 16) ^ ((sr & 7) << 4);
    const unsigned short* kbase = Kh + ((size_t)bh * 2048 + sr) * 64 + sc * 8;
    const unsigned short* vbase = Vt + ((size_t)bh * 64 + sr) * 2048 + sc * 8;

    // Q fragments in registers (A-frag: row=l16, k = g*8 + ks*32 + e)
    s16x8 qf[2];
    {
        const unsigned short* qp = Qh + ((size_t)bh * 2048 + qrow0 + l16) * 64 + g * 8;
        qf[0] = __builtin_bit_cast(s16x8, *(const u16x8*)qp);
        qf[1] = __builtin_bit_cast(s16x8, *(const u16x8*)(qp + 32));
    }

    f32x4 o[4] = {};
    float m[4], l[4];
    #pragma unroll
    for (int rr = 0; rr < 4; ++rr) { m[rr] = -3.0e38f; l[rr] = 0.f; }

    // prologue: stage tile 0 into buf 0
    *(u16x8*)((char*)Ksw[0] + soff) = *(const u16x8*)kbase;
    *(u16x8*)((char*)Vsw[0] + soff) = *(const u16x8*)vbase;
    __syncthreads();

    int cur = 0;
    for (int t = 0; t < ntile; ++t) {
        const int kv0 = t * 64;

        // issue next-tile loads EARLY (latency hides under compute)
        u16x8 kn, vn;
        const bool hn = (t + 1 < ntile);
        if (hn) {
            kn = *(const u16x8*)(kbase + (size_t)(kv0 + 64) * 64);
            vn = *(const u16x8*)(vbase + (kv0 + 64));
        }

        if (kv0 <= qrow0 + 15) {   // wave-uniform: skip fully-masked tiles
            const char* Kb = (const char*)Ksw[cur];
            const char* Vb = (const char*)Vsw[cur];

            // ---- S = Q K^T (rows q, cols kv) ----
            f32x4 s[4] = {};
            __builtin_amdgcn_s_setprio(1);
            #pragma unroll
            for (int nt = 0; nt < 4; ++nt) {
                #pragma unroll
                for (int ks = 0; ks < 2; ++ks) {
                    const int row = nt * 16 + l16;
                    const int off = (row * 128 + g * 16 + ks * 64) ^ ((row & 7) << 4);
                    s16x8 kf = __builtin_bit_cast(s16x8, *(const u16x8*)(Kb + off));
                    s[nt] = __builtin_amdgcn_mfma_f32_16x16x32_bf16(qf[ks], kf, s[nt], 0, 0, 0);
                }
            }
            __builtin_amdgcn_s_setprio(0);

            // ---- causal mask (only if tile touches diagonal) ----
            if (kv0 + 63 > qrow0) {
                #pragma unroll
                for (int nt = 0; nt < 4; ++nt)
                    #pragma unroll
                    for (int rr = 0; rr < 4; ++rr) {
                        const int kv_g = kv0 + nt * 16 + l16;
                        const int q_g  = qrow0 + g * 4 + rr;
                        if (kv_g > q_g) s[nt][rr] = -3.0e38f;
                    }
            }

            // ---- online softmax (rows on (g,rr); max-reduce over 16 lanes) ----
            float sc4[4];
            #pragma unroll
            for (int rr = 0; rr < 4; ++rr) {
                float tmax = fmaxf(fmaxf(s[0][rr], s[1][rr]), fmaxf(s[2][rr], s[3][rr]));
                tmax = fmaxf(tmax, __shfl_xor(tmax, 1));
                tmax = fmaxf(tmax, __shfl_xor(tmax, 2));
                tmax = fmaxf(tmax, __shfl_xor(tmax, 4));
                tmax = fmaxf(tmax, __shfl_xor(tmax, 8));
                const float mn = fmaxf(m[rr], tmax);
                sc4[rr] = __expf(m[rr] - mn);
                m[rr]  = mn;
                float r0 = 0.f;
                #pragma unroll
                for (int nt = 0; nt < 4; ++nt) {
                    const float p = __expf(s[nt][rr] - mn);
                    s[nt][rr] = p;
                    r0 += p;
                }
                l[rr] = l[rr] * sc4[rr] + r0;   // per-lane partial; reduced in epilogue
            }
            #pragma unroll
            for (int nt = 0; nt < 4; ++nt)
                #pragma unroll
                for (int rr = 0; rr < 4; ++rr)
                    o[nt][rr] *= sc4[rr];

            // ---- P -> per-wave LDS (bf16), then PV ----
            unsigned short* Pw = Psw[wave];
            #pragma unroll
            for (int nt = 0; nt < 4; ++nt)
                #pragma unroll
                for (int rr = 0; rr < 4; ++rr) {
                    const int qr  = g * 4 + rr;
                    const int off = (qr * 128 + (nt * 16 + l16) * 2) ^ ((qr & 7) << 4);
                    *(unsigned short*)((char*)Pw + off) = f2bf(s[nt][rr]);
                }
            // wave-private LDS: in-order per-wave DS pipe, no barrier

            __builtin_amdgcn_s_setprio(1);
            #pragma unroll
            for (int ks = 0; ks < 2; ++ks) {
                const int offp = (l16 * 128 + g * 16 + ks * 64) ^ ((l16 & 7) << 4);
                s16x8 pf = __builtin_bit_cast(s16x8, *(const u16x8*)((const char*)Pw + offp));
                #pragma unroll
                for (int nt = 0; nt < 4; ++nt) {
                    const int row = nt * 16 + l16;
                    const int off = (row * 128 + g * 16 + ks * 64) ^ ((row & 7) << 4);
                    s16x8 vf = __builtin_bit_cast(s16x8, *(const u16x8*)(Vb + off));
                    o[nt] = __builtin_amdgcn_mfma_f32_16x16x32_bf16(pf, vf, o[nt], 0, 0, 0);
                }
            }
            __builtin_amdgcn_s_setprio(0);
        }

        // write next tile into the other buffer, single barrier per iter
        if (hn) {
            *(u16x8*)((char*)Ksw[cur ^ 1] + soff) = kn;
            *(u16x8*)((char*)Vsw[cur ^ 1] + soff) = vn;
        }
        __syncthreads();
        cur ^= 1;
    }

    // ---- epilogue: reduce l across 16-lane group, write ctx ----
    #pragma unroll
    for (int rr = 0; rr < 4; ++rr) {
        float ls = l[rr];
        ls += __shfl_xor(ls, 1);
        ls += __shfl_xor(ls, 2);
        ls += __shfl_xor(ls, 4);
        ls += __shfl_xor(ls, 8);
        const float inv = 1.0f / ls;
        const int q_g = qrow0 + g * 4 + rr;
        #pragma unroll
        for (int nt = 0; nt < 4; ++nt) {
            const int d = nt * 16 + l16;
            Ctx[((size_t)b * 2048 + q_g) * 1024 + h * 64 + d] = f2bf(o[nt][rr] * inv);
        }
    }
}

// =====================================================================
extern "C" void kernel_launch(void* const* d_in, const int* in_sizes, int n_in,
                              void* d_out, int out_size, void* d_ws, size_t ws_size,
                              hipStream_t stream)
{
    const float* q  = (const float*)d_in[0];
    const float* k  = (const float*)d_in[1];
    const float* v  = (const float*)d_in[2];
    // d_in[3] = mask (causal tril, known statically) — unused
    const float* Wq = (const float*)d_in[4];
    const float* Wk = (const float*)d_in[5];
    const float* Wv = (const float*)d_in[6];
    const float* Wo = (const float*)d_in[7];

    const size_t NE = (size_t)4 * 16 * 2048 * 64;     // 8,388,608 elems per tensor
    unsigned short* Qh  = (unsigned short*)d_ws;
    unsigned short* Kh  = Qh + NE;
    unsigned short* Vt  = Kh + NE;
    unsigned short* Ctx = Vt + NE;

    dim3 blk(256);
    proj_kernel<0><<<dim3(512), blk, 0, stream>>>(q, Wq, Qh);
    proj_kernel<1><<<dim3(512), blk, 0, stream>>>(k, Wk, Kh);
    proj_kernel<2><<<dim3(512), blk, 0, stream>>>(v, Wv, Vt);
    attn_kernel   <<<dim3(1024), dim3(512), 0, stream>>>(Qh, Kh, Vt, Ctx);
    proj_kernel<3><<<dim3(512), blk, 0, stream>>>(Ctx, Wo, (float*)d_out);
}

// Round 3
// 233.611 us; speedup vs baseline: 2.3162x; 1.4065x over previous
//
#include <hip/hip_runtime.h>

// ---------- types ----------
typedef __attribute__((ext_vector_type(4))) float  f32x4;
typedef __attribute__((ext_vector_type(8))) short  s16x8;   // 8 bf16 (4 VGPRs)
typedef __attribute__((ext_vector_type(8))) unsigned short u16x8;

static __device__ __forceinline__ unsigned short f2bf(float f) {
    unsigned int u = __builtin_bit_cast(unsigned int, f);
    u += 0x7fffu + ((u >> 16) & 1u);      // round-to-nearest-even
    return (unsigned short)(u >> 16);
}

static __device__ __forceinline__ void gload16(const void* g, void* l) {
    __builtin_amdgcn_global_load_lds(
        (const __attribute__((address_space(1))) void*)g,
        (__attribute__((address_space(3))) void*)l, 16, 0, 0);
}

// =====================================================================
// fp32 -> bf16 convert pass. ALLMODE=1: q,k,v + 4 weights; 0: weights only.
// Each block converts 2048 elems (256 thr x 8).
// =====================================================================
template<int ALLMODE>
__global__ __launch_bounds__(256)
void conv_kernel(const float* __restrict__ q, const float* __restrict__ k,
                 const float* __restrict__ v,
                 const float* __restrict__ wq, const float* __restrict__ wk,
                 const float* __restrict__ wv, const float* __restrict__ wo,
                 unsigned short* __restrict__ qb, unsigned short* __restrict__ kb,
                 unsigned short* __restrict__ vb, unsigned short* __restrict__ wb)
{
    const int bid = blockIdx.x;
    const float* src; unsigned short* dst; int inner;
    if (ALLMODE) {
        if      (bid < 4096)  { src = q;  dst = qb; inner = bid; }
        else if (bid < 8192)  { src = k;  dst = kb; inner = bid - 4096; }
        else if (bid < 12288) { src = v;  dst = vb; inner = bid - 8192; }
        else {
            const int wseg = (bid - 12288) >> 9;
            src = wseg == 0 ? wq : wseg == 1 ? wk : wseg == 2 ? wv : wo;
            dst = wb + (size_t)wseg * 1048576;
            inner = (bid - 12288) & 511;
        }
    } else {
        const int wseg = bid >> 9;
        src = wseg == 0 ? wq : wseg == 1 ? wk : wseg == 2 ? wv : wo;
        dst = wb + (size_t)wseg * 1048576;
        inner = bid & 511;
    }
    const size_t e0 = (size_t)inner * 2048 + threadIdx.x * 8;
    f32x4 a = *(const f32x4*)(src + e0);
    f32x4 b = *(const f32x4*)(src + e0 + 4);
    u16x8 o;
    #pragma unroll
    for (int i = 0; i < 4; ++i) { o[i] = f2bf(a[i]); o[i + 4] = f2bf(b[i]); }
    *(u16x8*)(dst + e0) = o;
}

// =====================================================================
// NT GEMM, 128x128 tile, BK=64, 4 waves, swizzled LDS.
// AM/BM: 0 = bf16 input staged via global_load_lds (pre-swizzled source),
//        1 = fp32 input, reg-staged + converted + swizzled ds_write.
// EPI 0: fused QKV (grid 1536 = 192 by x 8 bx, seg = by>>6):
//        seg0 -> Qh [B,H,L,64] * 0.125 ; seg1 -> Kh ; seg2 -> Vt [B,H,64,L]
// EPI 1: out proj (grid 512): fp32 [8192,1024]
// =====================================================================
template<int AM, int BM, int EPI>
__global__ __launch_bounds__(256)
void gemm_k(const void* __restrict__ A0, const void* __restrict__ A1,
            const void* __restrict__ A2,
            const void* __restrict__ B0, const void* __restrict__ B1,
            const void* __restrict__ B2,
            unsigned short* __restrict__ O0, unsigned short* __restrict__ O1,
            unsigned short* __restrict__ O2, float* __restrict__ Of)
{
    __shared__ unsigned short Asw[128 * 64];
    __shared__ unsigned short Bsw[128 * 64];

    const int tid  = threadIdx.x;
    const int lane = tid & 63;
    const int wave = tid >> 6;
    const int wr   = wave >> 1, wc = wave & 1;
    const int g    = lane >> 4, l16 = lane & 15;

    // bijective XCD swizzle (grid % 8 == 0)
    const int nper = (EPI == 0) ? 192 : 64;
    const int wg   = (blockIdx.x & 7) * nper + (blockIdx.x >> 3);
    const int bx   = wg & 7;
    const int by   = wg >> 3;
    const int seg  = (EPI == 0) ? (by >> 6) : 0;
    const int byl  = (EPI == 0) ? (by & 63) : by;

    const void* Ap = seg == 0 ? A0 : seg == 1 ? A1 : A2;
    const void* Bp = seg == 0 ? B0 : seg == 1 ? B1 : B2;

    f32x4 acc[4][4] = {};

    for (int kt = 0; kt < 16; ++kt) {
        __syncthreads();
        // ---- stage A tile (rows = M) ----
        if (AM == 0) {
            #pragma unroll
            for (int j = 0; j < 4; ++j) {
                const int idx = j * 256 + tid;
                const int r   = idx >> 3;
                const int cl  = (tid & 7) ^ (r & 7);     // inverse-swizzled source chunk
                const unsigned short* src = (const unsigned short*)Ap
                    + (size_t)(byl * 128 + r) * 1024 + kt * 64 + cl * 8;
                gload16(src, (char*)Asw + j * 4096 + wave * 1024);
            }
        } else {
            #pragma unroll
            for (int j = 0; j < 4; ++j) {
                const int idx = j * 256 + tid;
                const int r = idx >> 3, c = tid & 7;
                const float* src = (const float*)Ap
                    + (size_t)(byl * 128 + r) * 1024 + kt * 64 + c * 8;
                f32x4 a = *(const f32x4*)src;
                f32x4 b = *(const f32x4*)(src + 4);
                u16x8 w;
                #pragma unroll
                for (int i = 0; i < 4; ++i) { w[i] = f2bf(a[i]); w[i + 4] = f2bf(b[i]); }
                *(u16x8*)((char*)Asw + ((r * 128 + c * 16) ^ ((r & 7) << 4))) = w;
            }
        }
        // ---- stage B tile (rows = N) ----
        if (BM == 0) {
            #pragma unroll
            for (int j = 0; j < 4; ++j) {
                const int idx = j * 256 + tid;
                const int r   = idx >> 3;
                const int cl  = (tid & 7) ^ (r & 7);
                const unsigned short* src = (const unsigned short*)Bp
                    + (size_t)(bx * 128 + r) * 1024 + kt * 64 + cl * 8;
                gload16(src, (char*)Bsw + j * 4096 + wave * 1024);
            }
        } else {
            #pragma unroll
            for (int j = 0; j < 4; ++j) {
                const int idx = j * 256 + tid;
                const int r = idx >> 3, c = tid & 7;
                const float* src = (const float*)Bp
                    + (size_t)(bx * 128 + r) * 1024 + kt * 64 + c * 8;
                f32x4 a = *(const f32x4*)src;
                f32x4 b = *(const f32x4*)(src + 4);
                u16x8 w;
                #pragma unroll
                for (int i = 0; i < 4; ++i) { w[i] = f2bf(a[i]); w[i + 4] = f2bf(b[i]); }
                *(u16x8*)((char*)Bsw + ((r * 128 + c * 16) ^ ((r & 7) << 4))) = w;
            }
        }
        __syncthreads();

        // ---- compute ----
        #pragma unroll
        for (int ks = 0; ks < 2; ++ks) {
            s16x8 af[4], bf[4];
            #pragma unroll
            for (int mi = 0; mi < 4; ++mi) {
                const int row = wr * 64 + mi * 16 + l16;
                const int off = (row * 128 + g * 16 + ks * 64) ^ ((row & 7) << 4);
                af[mi] = __builtin_bit_cast(s16x8, *(const u16x8*)((const char*)Asw + off));
            }
            #pragma unroll
            for (int ni = 0; ni < 4; ++ni) {
                const int row = wc * 64 + ni * 16 + l16;
                const int off = (row * 128 + g * 16 + ks * 64) ^ ((row & 7) << 4);
                bf[ni] = __builtin_bit_cast(s16x8, *(const u16x8*)((const char*)Bsw + off));
            }
            __builtin_amdgcn_s_setprio(1);
            #pragma unroll
            for (int mi = 0; mi < 4; ++mi)
                #pragma unroll
                for (int ni = 0; ni < 4; ++ni)
                    acc[mi][ni] = __builtin_amdgcn_mfma_f32_16x16x32_bf16(
                        af[mi], bf[ni], acc[mi][ni], 0, 0, 0);
            __builtin_amdgcn_s_setprio(0);
        }
    }

    // ---- epilogue ----
    #pragma unroll
    for (int mi = 0; mi < 4; ++mi) {
        #pragma unroll
        for (int ni = 0; ni < 4; ++ni) {
            #pragma unroll
            for (int rr = 0; rr < 4; ++rr) {
                const int gr = byl * 128 + wr * 64 + mi * 16 + g * 4 + rr; // M
                const int gc = bx * 128 + wc * 64 + ni * 16 + l16;         // N
                float v = acc[mi][ni][rr];
                if (EPI == 0) {
                    const int b = gr >> 11, ll = gr & 2047, h = gc >> 6, dh = gc & 63;
                    if (seg == 0) {
                        v *= 0.125f;  // 1/sqrt(DH)
                        O0[(size_t)((b * 16 + h) * 2048 + ll) * 64 + dh] = f2bf(v);
                    } else if (seg == 1) {
                        O1[(size_t)((b * 16 + h) * 2048 + ll) * 64 + dh] = f2bf(v);
                    } else {
                        O2[(size_t)((b * 16 + h) * 64 + dh) * 2048 + ll] = f2bf(v);
                    }
                } else {
                    Of[(size_t)gr * 1024 + gc] = v;
                }
            }
        }
    }
}

// =====================================================================
// Flash-style causal attention, double-buffered KV. (unchanged from R2)
// Qh,Kh: [B,H,L,64] bf16 (Q pre-scaled by 1/8); Vt: [B,H,64,L] bf16
// Block = 512 thr (8 waves) owns 128 q rows of one (b,h); wave w owns 16.
// =====================================================================
__global__ __launch_bounds__(512)
void attn_kernel(const unsigned short* __restrict__ Qh,
                 const unsigned short* __restrict__ Kh,
                 const unsigned short* __restrict__ Vt,
                 unsigned short* __restrict__ Ctx)
{
    __shared__ unsigned short Ksw[2][64 * 64];
    __shared__ unsigned short Vsw[2][64 * 64];
    __shared__ unsigned short Psw[8][16 * 64];

    const int tid  = threadIdx.x;
    const int lane = tid & 63;
    const int wave = tid >> 6;
    const int g    = lane >> 4, l16 = lane & 15;
    const int qb   = 15 - (int)(blockIdx.x >> 6);
    const int bh   = blockIdx.x & 63;
    const int b    = bh >> 4, h = bh & 15;
    const int qrow0 = qb * 128 + wave * 16;
    const int ntile = 2 * qb + 2;

    const int sr = tid >> 3, sc = tid & 7;
    const int soff = (sr * 128 + sc * 16) ^ ((sr & 7) << 4);
    const unsigned short* kbase = Kh + ((size_t)bh * 2048 + sr) * 64 + sc * 8;
    const unsigned short* vbase = Vt + ((size_t)bh * 64 + sr) * 2048 + sc * 8;

    s16x8 qf[2];
    {
        const unsigned short* qp = Qh + ((size_t)bh * 2048 + qrow0 + l16) * 64 + g * 8;
        qf[0] = __builtin_bit_cast(s16x8, *(const u16x8*)qp);
        qf[1] = __builtin_bit_cast(s16x8, *(const u16x8*)(qp + 32));
    }

    f32x4 o[4] = {};
    float m[4], l[4];
    #pragma unroll
    for (int rr = 0; rr < 4; ++rr) { m[rr] = -3.0e38f; l[rr] = 0.f; }

    *(u16x8*)((char*)Ksw[0] + soff) = *(const u16x8*)kbase;
    *(u16x8*)((char*)Vsw[0] + soff) = *(const u16x8*)vbase;
    __syncthreads();

    int cur = 0;
    for (int t = 0; t < ntile; ++t) {
        const int kv0 = t * 64;

        u16x8 kn, vn;
        const bool hn = (t + 1 < ntile);
        if (hn) {
            kn = *(const u16x8*)(kbase + (size_t)(kv0 + 64) * 64);
            vn = *(const u16x8*)(vbase + (kv0 + 64));
        }

        if (kv0 <= qrow0 + 15) {
            const char* Kb = (const char*)Ksw[cur];
            const char* Vb = (const char*)Vsw[cur];

            f32x4 s[4] = {};
            __builtin_amdgcn_s_setprio(1);
            #pragma unroll
            for (int nt = 0; nt < 4; ++nt) {
                #pragma unroll
                for (int ks = 0; ks < 2; ++ks) {
                    const int row = nt * 16 + l16;
                    const int off = (row * 128 + g * 16 + ks * 64) ^ ((row & 7) << 4);
                    s16x8 kf = __builtin_bit_cast(s16x8, *(const u16x8*)(Kb + off));
                    s[nt] = __builtin_amdgcn_mfma_f32_16x16x32_bf16(qf[ks], kf, s[nt], 0, 0, 0);
                }
            }
            __builtin_amdgcn_s_setprio(0);

            if (kv0 + 63 > qrow0) {
                #pragma unroll
                for (int nt = 0; nt < 4; ++nt)
                    #pragma unroll
                    for (int rr = 0; rr < 4; ++rr) {
                        const int kv_g = kv0 + nt * 16 + l16;
                        const int q_g  = qrow0 + g * 4 + rr;
                        if (kv_g > q_g) s[nt][rr] = -3.0e38f;
                    }
            }

            float sc4[4];
            #pragma unroll
            for (int rr = 0; rr < 4; ++rr) {
                float tmax = fmaxf(fmaxf(s[0][rr], s[1][rr]), fmaxf(s[2][rr], s[3][rr]));
                tmax = fmaxf(tmax, __shfl_xor(tmax, 1));
                tmax = fmaxf(tmax, __shfl_xor(tmax, 2));
                tmax = fmaxf(tmax, __shfl_xor(tmax, 4));
                tmax = fmaxf(tmax, __shfl_xor(tmax, 8));
                const float mn = fmaxf(m[rr], tmax);
                sc4[rr] = __expf(m[rr] - mn);
                m[rr]  = mn;
                float r0 = 0.f;
                #pragma unroll
                for (int nt = 0; nt < 4; ++nt) {
                    const float p = __expf(s[nt][rr] - mn);
                    s[nt][rr] = p;
                    r0 += p;
                }
                l[rr] = l[rr] * sc4[rr] + r0;
            }
            #pragma unroll
            for (int nt = 0; nt < 4; ++nt)
                #pragma unroll
                for (int rr = 0; rr < 4; ++rr)
                    o[nt][rr] *= sc4[rr];

            unsigned short* Pw = Psw[wave];
            #pragma unroll
            for (int nt = 0; nt < 4; ++nt)
                #pragma unroll
                for (int rr = 0; rr < 4; ++rr) {
                    const int qr  = g * 4 + rr;
                    const int off = (qr * 128 + (nt * 16 + l16) * 2) ^ ((qr & 7) << 4);
                    *(unsigned short*)((char*)Pw + off) = f2bf(s[nt][rr]);
                }

            __builtin_amdgcn_s_setprio(1);
            #pragma unroll
            for (int ks = 0; ks < 2; ++ks) {
                const int offp = (l16 * 128 + g * 16 + ks * 64) ^ ((l16 & 7) << 4);
                s16x8 pf = __builtin_bit_cast(s16x8, *(const u16x8*)((const char*)Pw + offp));
                #pragma unroll
                for (int nt = 0; nt < 4; ++nt) {
                    const int row = nt * 16 + l16;
                    const int off = (row * 128 + g * 16 + ks * 64) ^ ((row & 7) << 4);
                    s16x8 vf = __builtin_bit_cast(s16x8, *(const u16x8*)(Vb + off));
                    o[nt] = __builtin_amdgcn_mfma_f32_16x16x32_bf16(pf, vf, o[nt], 0, 0, 0);
                }
            }
            __builtin_amdgcn_s_setprio(0);
        }

        if (hn) {
            *(u16x8*)((char*)Ksw[cur ^ 1] + soff) = kn;
            *(u16x8*)((char*)Vsw[cur ^ 1] + soff) = vn;
        }
        __syncthreads();
        cur ^= 1;
    }

    #pragma unroll
    for (int rr = 0; rr < 4; ++rr) {
        float ls = l[rr];
        ls += __shfl_xor(ls, 1);
        ls += __shfl_xor(ls, 2);
        ls += __shfl_xor(ls, 4);
        ls += __shfl_xor(ls, 8);
        const float inv = 1.0f / ls;
        const int q_g = qrow0 + g * 4 + rr;
        #pragma unroll
        for (int nt = 0; nt < 4; ++nt) {
            const int d = nt * 16 + l16;
            Ctx[((size_t)b * 2048 + q_g) * 1024 + h * 64 + d] = f2bf(o[nt][rr] * inv);
        }
    }
}

// =====================================================================
extern "C" void kernel_launch(void* const* d_in, const int* in_sizes, int n_in,
                              void* d_out, int out_size, void* d_ws, size_t ws_size,
                              hipStream_t stream)
{
    const float* q  = (const float*)d_in[0];
    const float* k  = (const float*)d_in[1];
    const float* v  = (const float*)d_in[2];
    const float* Wq = (const float*)d_in[4];
    const float* Wk = (const float*)d_in[5];
    const float* Wv = (const float*)d_in[6];
    const float* Wo = (const float*)d_in[7];

    const size_t NE = (size_t)4 * 16 * 2048 * 64;     // 8,388,608 elems / tensor
    const size_t WE = (size_t)1024 * 1024;            // 1,048,576 elems / weight
    unsigned short* Qh = (unsigned short*)d_ws;
    unsigned short* Kh = Qh + NE;
    unsigned short* Vt = Kh + NE;
    float* outp = (float*)d_out;
    dim3 blk(256);

    if (ws_size >= 6 * NE * 2 + 4 * WE * 2) {
        // ---- tier 1: full bf16 pre-convert ----
        unsigned short* qb  = Vt + NE;      // Ctx aliases qb (dead after QKV gemm)
        unsigned short* kb  = qb + NE;
        unsigned short* vb  = kb + NE;
        unsigned short* wb  = vb + NE;
        unsigned short* Ctx = qb;
        conv_kernel<1><<<dim3(14336), blk, 0, stream>>>(q, k, v, Wq, Wk, Wv, Wo,
                                                        qb, kb, vb, wb);
        gemm_k<0, 0, 0><<<dim3(1536), blk, 0, stream>>>(
            qb, kb, vb, wb, wb + WE, wb + 2 * WE, Qh, Kh, Vt, nullptr);
        attn_kernel<<<dim3(1024), dim3(512), 0, stream>>>(Qh, Kh, Vt, Ctx);
        gemm_k<0, 0, 1><<<dim3(512), blk, 0, stream>>>(
            Ctx, nullptr, nullptr, wb + 3 * WE, nullptr, nullptr,
            nullptr, nullptr, nullptr, outp);
    } else if (ws_size >= 4 * NE * 2 + 4 * WE * 2) {
        // ---- tier 2: weights-only pre-convert ----
        unsigned short* Ctx = Vt + NE;
        unsigned short* wb  = Ctx + NE;
        conv_kernel<0><<<dim3(2048), blk, 0, stream>>>(q, k, v, Wq, Wk, Wv, Wo,
                                                       nullptr, nullptr, nullptr, wb);
        gemm_k<1, 0, 0><<<dim3(1536), blk, 0, stream>>>(
            q, k, v, wb, wb + WE, wb + 2 * WE, Qh, Kh, Vt, nullptr);
        attn_kernel<<<dim3(1024), dim3(512), 0, stream>>>(Qh, Kh, Vt, Ctx);
        gemm_k<0, 0, 1><<<dim3(512), blk, 0, stream>>>(
            Ctx, nullptr, nullptr, wb + 3 * WE, nullptr, nullptr,
            nullptr, nullptr, nullptr, outp);
    } else {
        // ---- tier 3: convert everything in-GEMM (proven 67.1 MB footprint) ----
        unsigned short* Ctx = Vt + NE;
        gemm_k<1, 1, 0><<<dim3(1536), blk, 0, stream>>>(
            q, k, v, Wq, Wk, Wv, Qh, Kh, Vt, nullptr);
        attn_kernel<<<dim3(1024), dim3(512), 0, stream>>>(Qh, Kh, Vt, Ctx);
        gemm_k<0, 1, 1><<<dim3(512), blk, 0, stream>>>(
            Ctx, nullptr, nullptr, Wo, nullptr, nullptr,
            nullptr, nullptr, nullptr, outp);
    }
}

// Round 4
// 225.212 us; speedup vs baseline: 2.4026x; 1.0373x over previous
//
#include <hip/hip_runtime.h>

// ---------- types ----------
typedef __attribute__((ext_vector_type(4))) float  f32x4;
typedef __attribute__((ext_vector_type(8))) short  s16x8;   // 8 bf16 (4 VGPRs)
typedef __attribute__((ext_vector_type(8))) unsigned short u16x8;
typedef __attribute__((ext_vector_type(4))) unsigned short u16x4;

static __device__ __forceinline__ unsigned short f2bf(float f) {
    unsigned int u = __builtin_bit_cast(unsigned int, f);
    u += 0x7fffu + ((u >> 16) & 1u);      // round-to-nearest-even
    return (unsigned short)(u >> 16);
}

static __device__ __forceinline__ void gload16(const void* g, void* l) {
    __builtin_amdgcn_global_load_lds(
        (const __attribute__((address_space(1))) void*)g,
        (__attribute__((address_space(3))) void*)l, 16, 0, 0);
}

// =====================================================================
// fp32 -> bf16 convert pass: q,k,v + 4 weights. 2048 elems/block.
// =====================================================================
__global__ __launch_bounds__(256)
void conv_kernel(const float* __restrict__ q, const float* __restrict__ k,
                 const float* __restrict__ v,
                 const float* __restrict__ wq, const float* __restrict__ wk,
                 const float* __restrict__ wv, const float* __restrict__ wo,
                 unsigned short* __restrict__ qb, unsigned short* __restrict__ kb,
                 unsigned short* __restrict__ vb, unsigned short* __restrict__ wb)
{
    const int bid = blockIdx.x;
    const float* src; unsigned short* dst; int inner;
    if      (bid < 4096)  { src = q;  dst = qb; inner = bid; }
    else if (bid < 8192)  { src = k;  dst = kb; inner = bid - 4096; }
    else if (bid < 12288) { src = v;  dst = vb; inner = bid - 8192; }
    else {
        const int wseg = (bid - 12288) >> 9;
        src = wseg == 0 ? wq : wseg == 1 ? wk : wseg == 2 ? wv : wo;
        dst = wb + (size_t)wseg * 1048576;
        inner = (bid - 12288) & 511;
    }
    const size_t e0 = (size_t)inner * 2048 + threadIdx.x * 8;
    f32x4 a = *(const f32x4*)(src + e0);
    f32x4 b = *(const f32x4*)(src + e0 + 4);
    u16x8 o;
    #pragma unroll
    for (int i = 0; i < 4; ++i) { o[i] = f2bf(a[i]); o[i + 4] = f2bf(b[i]); }
    *(u16x8*)(dst + e0) = o;
}

// =====================================================================
// bf16 NT GEMM, 256x128 tile, BK=64, 8 waves, double-buffered LDS,
// stage-ahead (T3-min): STAGE(next) -> ds_read+MFMA(cur) -> vmcnt(0) -> bar.
// EPI 0: fused QKV. grid 768 (= 3 seg x 32 by x 8 bx), XCD-swizzled.
//        seg0 -> Qh [B,H,L,64] * 0.125 ; seg1 -> Kh ; seg2 -> Vt [B,H,64,L]
// EPI 1: out proj. grid 256. Of fp32 [8192,1024].
// =====================================================================
template<int EPI>
__global__ __launch_bounds__(512)
void gemm2(const unsigned short* __restrict__ A0,
           const unsigned short* __restrict__ A1,
           const unsigned short* __restrict__ A2,
           const unsigned short* __restrict__ Bw,
           unsigned short* __restrict__ O0, unsigned short* __restrict__ O1,
           unsigned short* __restrict__ O2, float* __restrict__ Of)
{
    __shared__ unsigned short Asw[2][256 * 64];   // 64 KB
    __shared__ unsigned short Bsw[2][128 * 64];   // 32 KB

    const int tid  = threadIdx.x;
    const int lane = tid & 63;
    const int wave = tid >> 6;
    const int wr   = wave >> 1, wc = wave & 1;    // 4 x 2 wave grid, 64x64 each
    const int g    = lane >> 4, l16 = lane & 15;

    const int nblk = (EPI == 0) ? 768 : 256;
    const int cpx  = nblk >> 3;
    const int wg   = (blockIdx.x & 7) * cpx + (blockIdx.x >> 3);  // bijective XCD swizzle
    const int bx   = wg & 7;
    const int byt  = wg >> 3;
    const int seg  = (EPI == 0) ? (byt >> 5) : 0;
    const int byl  = (EPI == 0) ? (byt & 31) : byt;

    const unsigned short* Ap = (EPI == 0) ? (seg == 0 ? A0 : seg == 1 ? A1 : A2) : A0;
    const unsigned short* Arow = Ap + (size_t)(byl * 256) * 1024;
    const unsigned short* Brow = Bw + (size_t)seg * 1048576 + (size_t)(bx * 128) * 1024;

    f32x4 acc[4][4] = {};

    // stage one K-tile (256x64 A + 128x64 B) into buffer `buf`.
    // linear LDS dest (gload_lds), inverse-swizzled global source (rule 21).
    auto stage = [&](int buf, int kt) {
        #pragma unroll
        for (int j = 0; j < 4; ++j) {
            const int idx = j * 512 + tid;
            const int r   = idx >> 3;
            const int cl  = (tid & 7) ^ (r & 7);
            gload16(Arow + (size_t)r * 1024 + kt * 64 + cl * 8,
                    (char*)Asw[buf] + j * 8192 + wave * 1024);
        }
        #pragma unroll
        for (int j = 0; j < 2; ++j) {
            const int idx = j * 512 + tid;
            const int r   = idx >> 3;
            const int cl  = (tid & 7) ^ (r & 7);
            gload16(Brow + (size_t)r * 1024 + kt * 64 + cl * 8,
                    (char*)Bsw[buf] + j * 8192 + wave * 1024);
        }
    };

    stage(0, 0);
    asm volatile("s_waitcnt vmcnt(0)" ::: "memory");
    __builtin_amdgcn_s_barrier();

    int cur = 0;
    for (int kt = 0; kt < 16; ++kt) {
        if (kt < 15) stage(cur ^ 1, kt + 1);   // issue next-tile loads EARLY

        const char* Ab = (const char*)Asw[cur];
        const char* Bb = (const char*)Bsw[cur];
        #pragma unroll
        for (int ks = 0; ks < 2; ++ks) {
            s16x8 af[4], bf[4];
            #pragma unroll
            for (int mi = 0; mi < 4; ++mi) {
                const int row = wr * 64 + mi * 16 + l16;
                const int off = (row * 128 + g * 16 + ks * 64) ^ ((row & 7) << 4);
                af[mi] = __builtin_bit_cast(s16x8, *(const u16x8*)(Ab + off));
            }
            #pragma unroll
            for (int ni = 0; ni < 4; ++ni) {
                const int row = wc * 64 + ni * 16 + l16;
                const int off = (row * 128 + g * 16 + ks * 64) ^ ((row & 7) << 4);
                bf[ni] = __builtin_bit_cast(s16x8, *(const u16x8*)(Bb + off));
            }
            #pragma unroll
            for (int mi = 0; mi < 4; ++mi)
                #pragma unroll
                for (int ni = 0; ni < 4; ++ni)
                    acc[mi][ni] = __builtin_amdgcn_mfma_f32_16x16x32_bf16(
                        af[mi], bf[ni], acc[mi][ni], 0, 0, 0);
        }

        asm volatile("s_waitcnt vmcnt(0)" ::: "memory");  // next tile staged
        __builtin_amdgcn_s_barrier();
        cur ^= 1;
    }

    // ---- epilogue ----
    #pragma unroll
    for (int mi = 0; mi < 4; ++mi) {
        #pragma unroll
        for (int ni = 0; ni < 4; ++ni) {
            const int gr0 = byl * 256 + wr * 64 + mi * 16 + g * 4;      // M base
            const int gc  = bx * 128 + wc * 64 + ni * 16 + l16;         // N
            if (EPI == 0 && seg == 2) {
                // Vt [B,H,64,L]: pack 4 consecutive ll into one 8B store
                const int b = gr0 >> 11, ll = gr0 & 2047;
                const int h = gc >> 6,  dh = gc & 63;
                u16x4 pk;
                #pragma unroll
                for (int rr = 0; rr < 4; ++rr) pk[rr] = f2bf(acc[mi][ni][rr]);
                *(u16x4*)(O2 + (size_t)((b * 16 + h) * 64 + dh) * 2048 + ll) = pk;
            } else {
                #pragma unroll
                for (int rr = 0; rr < 4; ++rr) {
                    const int gr = gr0 + rr;
                    float v = acc[mi][ni][rr];
                    if (EPI == 0) {
                        const int b = gr >> 11, ll = gr & 2047;
                        const int h = gc >> 6,  dh = gc & 63;
                        if (seg == 0) {
                            v *= 0.125f;
                            O0[(size_t)((b * 16 + h) * 2048 + ll) * 64 + dh] = f2bf(v);
                        } else {
                            O1[(size_t)((b * 16 + h) * 2048 + ll) * 64 + dh] = f2bf(v);
                        }
                    } else {
                        Of[(size_t)gr * 1024 + gc] = v;
                    }
                }
            }
        }
    }
}

// =====================================================================
// Fallback GEMM (fp32 inputs converted in-loop) — only used if ws too small.
// =====================================================================
template<int AM, int BM, int EPI>
__global__ __launch_bounds__(256)
void gemm_k(const void* __restrict__ A0, const void* __restrict__ A1,
            const void* __restrict__ A2,
            const void* __restrict__ B0, const void* __restrict__ B1,
            const void* __restrict__ B2,
            unsigned short* __restrict__ O0, unsigned short* __restrict__ O1,
            unsigned short* __restrict__ O2, float* __restrict__ Of)
{
    __shared__ unsigned short Asw[128 * 64];
    __shared__ unsigned short Bsw[128 * 64];

    const int tid  = threadIdx.x;
    const int lane = tid & 63;
    const int wave = tid >> 6;
    const int wr   = wave >> 1, wc = wave & 1;
    const int g    = lane >> 4, l16 = lane & 15;

    const int nper = (EPI == 0) ? 192 : 64;
    const int wg   = (blockIdx.x & 7) * nper + (blockIdx.x >> 3);
    const int bx   = wg & 7;
    const int by   = wg >> 3;
    const int seg  = (EPI == 0) ? (by >> 6) : 0;
    const int byl  = (EPI == 0) ? (by & 63) : by;

    const void* Ap = seg == 0 ? A0 : seg == 1 ? A1 : A2;
    const void* Bp = seg == 0 ? B0 : seg == 1 ? B1 : B2;

    f32x4 acc[4][4] = {};

    for (int kt = 0; kt < 16; ++kt) {
        __syncthreads();
        if (AM == 0) {
            #pragma unroll
            for (int j = 0; j < 4; ++j) {
                const int idx = j * 256 + tid;
                const int r   = idx >> 3;
                const int cl  = (tid & 7) ^ (r & 7);
                gload16((const unsigned short*)Ap + (size_t)(byl * 128 + r) * 1024 + kt * 64 + cl * 8,
                        (char*)Asw + j * 4096 + wave * 1024);
            }
        } else {
            #pragma unroll
            for (int j = 0; j < 4; ++j) {
                const int idx = j * 256 + tid;
                const int r = idx >> 3, c = tid & 7;
                const float* src = (const float*)Ap + (size_t)(byl * 128 + r) * 1024 + kt * 64 + c * 8;
                f32x4 a = *(const f32x4*)src;
                f32x4 b = *(const f32x4*)(src + 4);
                u16x8 w;
                #pragma unroll
                for (int i = 0; i < 4; ++i) { w[i] = f2bf(a[i]); w[i + 4] = f2bf(b[i]); }
                *(u16x8*)((char*)Asw + ((r * 128 + c * 16) ^ ((r & 7) << 4))) = w;
            }
        }
        if (BM == 0) {
            #pragma unroll
            for (int j = 0; j < 4; ++j) {
                const int idx = j * 256 + tid;
                const int r   = idx >> 3;
                const int cl  = (tid & 7) ^ (r & 7);
                gload16((const unsigned short*)Bp + (size_t)(bx * 128 + r) * 1024 + kt * 64 + cl * 8,
                        (char*)Bsw + j * 4096 + wave * 1024);
            }
        } else {
            #pragma unroll
            for (int j = 0; j < 4; ++j) {
                const int idx = j * 256 + tid;
                const int r = idx >> 3, c = tid & 7;
                const float* src = (const float*)Bp + (size_t)(bx * 128 + r) * 1024 + kt * 64 + c * 8;
                f32x4 a = *(const f32x4*)src;
                f32x4 b = *(const f32x4*)(src + 4);
                u16x8 w;
                #pragma unroll
                for (int i = 0; i < 4; ++i) { w[i] = f2bf(a[i]); w[i + 4] = f2bf(b[i]); }
                *(u16x8*)((char*)Bsw + ((r * 128 + c * 16) ^ ((r & 7) << 4))) = w;
            }
        }
        __syncthreads();

        #pragma unroll
        for (int ks = 0; ks < 2; ++ks) {
            s16x8 af[4], bf[4];
            #pragma unroll
            for (int mi = 0; mi < 4; ++mi) {
                const int row = wr * 64 + mi * 16 + l16;
                const int off = (row * 128 + g * 16 + ks * 64) ^ ((row & 7) << 4);
                af[mi] = __builtin_bit_cast(s16x8, *(const u16x8*)((const char*)Asw + off));
            }
            #pragma unroll
            for (int ni = 0; ni < 4; ++ni) {
                const int row = wc * 64 + ni * 16 + l16;
                const int off = (row * 128 + g * 16 + ks * 64) ^ ((row & 7) << 4);
                bf[ni] = __builtin_bit_cast(s16x8, *(const u16x8*)((const char*)Bsw + off));
            }
            #pragma unroll
            for (int mi = 0; mi < 4; ++mi)
                #pragma unroll
                for (int ni = 0; ni < 4; ++ni)
                    acc[mi][ni] = __builtin_amdgcn_mfma_f32_16x16x32_bf16(
                        af[mi], bf[ni], acc[mi][ni], 0, 0, 0);
        }
    }

    #pragma unroll
    for (int mi = 0; mi < 4; ++mi) {
        #pragma unroll
        for (int ni = 0; ni < 4; ++ni) {
            #pragma unroll
            for (int rr = 0; rr < 4; ++rr) {
                const int gr = byl * 128 + wr * 64 + mi * 16 + g * 4 + rr;
                const int gc = bx * 128 + wc * 64 + ni * 16 + l16;
                float v = acc[mi][ni][rr];
                if (EPI == 0) {
                    const int b = gr >> 11, ll = gr & 2047, h = gc >> 6, dh = gc & 63;
                    if (seg == 0) {
                        v *= 0.125f;
                        O0[(size_t)((b * 16 + h) * 2048 + ll) * 64 + dh] = f2bf(v);
                    } else if (seg == 1) {
                        O1[(size_t)((b * 16 + h) * 2048 + ll) * 64 + dh] = f2bf(v);
                    } else {
                        O2[(size_t)((b * 16 + h) * 64 + dh) * 2048 + ll] = f2bf(v);
                    }
                } else {
                    Of[(size_t)gr * 1024 + gc] = v;
                }
            }
        }
    }
}

// =====================================================================
// Flash-style causal attention (unchanged from R2/R3).
// =====================================================================
__global__ __launch_bounds__(512)
void attn_kernel(const unsigned short* __restrict__ Qh,
                 const unsigned short* __restrict__ Kh,
                 const unsigned short* __restrict__ Vt,
                 unsigned short* __restrict__ Ctx)
{
    __shared__ unsigned short Ksw[2][64 * 64];
    __shared__ unsigned short Vsw[2][64 * 64];
    __shared__ unsigned short Psw[8][16 * 64];

    const int tid  = threadIdx.x;
    const int lane = tid & 63;
    const int wave = tid >> 6;
    const int g    = lane >> 4, l16 = lane & 15;
    const int qb   = 15 - (int)(blockIdx.x >> 6);
    const int bh   = blockIdx.x & 63;
    const int b    = bh >> 4, h = bh & 15;
    const int qrow0 = qb * 128 + wave * 16;
    const int ntile = 2 * qb + 2;

    const int sr = tid >> 3, sc = tid & 7;
    const int soff = (sr * 128 + sc * 16) ^ ((sr & 7) << 4);
    const unsigned short* kbase = Kh + ((size_t)bh * 2048 + sr) * 64 + sc * 8;
    const unsigned short* vbase = Vt + ((size_t)bh * 64 + sr) * 2048 + sc * 8;

    s16x8 qf[2];
    {
        const unsigned short* qp = Qh + ((size_t)bh * 2048 + qrow0 + l16) * 64 + g * 8;
        qf[0] = __builtin_bit_cast(s16x8, *(const u16x8*)qp);
        qf[1] = __builtin_bit_cast(s16x8, *(const u16x8*)(qp + 32));
    }

    f32x4 o[4] = {};
    float m[4], l[4];
    #pragma unroll
    for (int rr = 0; rr < 4; ++rr) { m[rr] = -3.0e38f; l[rr] = 0.f; }

    *(u16x8*)((char*)Ksw[0] + soff) = *(const u16x8*)kbase;
    *(u16x8*)((char*)Vsw[0] + soff) = *(const u16x8*)vbase;
    __syncthreads();

    int cur = 0;
    for (int t = 0; t < ntile; ++t) {
        const int kv0 = t * 64;

        u16x8 kn, vn;
        const bool hn = (t + 1 < ntile);
        if (hn) {
            kn = *(const u16x8*)(kbase + (size_t)(kv0 + 64) * 64);
            vn = *(const u16x8*)(vbase + (kv0 + 64));
        }

        if (kv0 <= qrow0 + 15) {
            const char* Kb = (const char*)Ksw[cur];
            const char* Vb = (const char*)Vsw[cur];

            f32x4 s[4] = {};
            __builtin_amdgcn_s_setprio(1);
            #pragma unroll
            for (int nt = 0; nt < 4; ++nt) {
                #pragma unroll
                for (int ks = 0; ks < 2; ++ks) {
                    const int row = nt * 16 + l16;
                    const int off = (row * 128 + g * 16 + ks * 64) ^ ((row & 7) << 4);
                    s16x8 kf = __builtin_bit_cast(s16x8, *(const u16x8*)(Kb + off));
                    s[nt] = __builtin_amdgcn_mfma_f32_16x16x32_bf16(qf[ks], kf, s[nt], 0, 0, 0);
                }
            }
            __builtin_amdgcn_s_setprio(0);

            if (kv0 + 63 > qrow0) {
                #pragma unroll
                for (int nt = 0; nt < 4; ++nt)
                    #pragma unroll
                    for (int rr = 0; rr < 4; ++rr) {
                        const int kv_g = kv0 + nt * 16 + l16;
                        const int q_g  = qrow0 + g * 4 + rr;
                        if (kv_g > q_g) s[nt][rr] = -3.0e38f;
                    }
            }

            float sc4[4];
            #pragma unroll
            for (int rr = 0; rr < 4; ++rr) {
                float tmax = fmaxf(fmaxf(s[0][rr], s[1][rr]), fmaxf(s[2][rr], s[3][rr]));
                tmax = fmaxf(tmax, __shfl_xor(tmax, 1));
                tmax = fmaxf(tmax, __shfl_xor(tmax, 2));
                tmax = fmaxf(tmax, __shfl_xor(tmax, 4));
                tmax = fmaxf(tmax, __shfl_xor(tmax, 8));
                const float mn = fmaxf(m[rr], tmax);
                sc4[rr] = __expf(m[rr] - mn);
                m[rr]  = mn;
                float r0 = 0.f;
                #pragma unroll
                for (int nt = 0; nt < 4; ++nt) {
                    const float p = __expf(s[nt][rr] - mn);
                    s[nt][rr] = p;
                    r0 += p;
                }
                l[rr] = l[rr] * sc4[rr] + r0;
            }
            #pragma unroll
            for (int nt = 0; nt < 4; ++nt)
                #pragma unroll
                for (int rr = 0; rr < 4; ++rr)
                    o[nt][rr] *= sc4[rr];

            unsigned short* Pw = Psw[wave];
            #pragma unroll
            for (int nt = 0; nt < 4; ++nt)
                #pragma unroll
                for (int rr = 0; rr < 4; ++rr) {
                    const int qr  = g * 4 + rr;
                    const int off = (qr * 128 + (nt * 16 + l16) * 2) ^ ((qr & 7) << 4);
                    *(unsigned short*)((char*)Pw + off) = f2bf(s[nt][rr]);
                }

            __builtin_amdgcn_s_setprio(1);
            #pragma unroll
            for (int ks = 0; ks < 2; ++ks) {
                const int offp = (l16 * 128 + g * 16 + ks * 64) ^ ((l16 & 7) << 4);
                s16x8 pf = __builtin_bit_cast(s16x8, *(const u16x8*)((const char*)Pw + offp));
                #pragma unroll
                for (int nt = 0; nt < 4; ++nt) {
                    const int row = nt * 16 + l16;
                    const int off = (row * 128 + g * 16 + ks * 64) ^ ((row & 7) << 4);
                    s16x8 vf = __builtin_bit_cast(s16x8, *(const u16x8*)(Vb + off));
                    o[nt] = __builtin_amdgcn_mfma_f32_16x16x32_bf16(pf, vf, o[nt], 0, 0, 0);
                }
            }
            __builtin_amdgcn_s_setprio(0);
        }

        if (hn) {
            *(u16x8*)((char*)Ksw[cur ^ 1] + soff) = kn;
            *(u16x8*)((char*)Vsw[cur ^ 1] + soff) = vn;
        }
        __syncthreads();
        cur ^= 1;
    }

    #pragma unroll
    for (int rr = 0; rr < 4; ++rr) {
        float ls = l[rr];
        ls += __shfl_xor(ls, 1);
        ls += __shfl_xor(ls, 2);
        ls += __shfl_xor(ls, 4);
        ls += __shfl_xor(ls, 8);
        const float inv = 1.0f / ls;
        const int q_g = qrow0 + g * 4 + rr;
        #pragma unroll
        for (int nt = 0; nt < 4; ++nt) {
            const int d = nt * 16 + l16;
            Ctx[((size_t)b * 2048 + q_g) * 1024 + h * 64 + d] = f2bf(o[nt][rr] * inv);
        }
    }
}

// =====================================================================
extern "C" void kernel_launch(void* const* d_in, const int* in_sizes, int n_in,
                              void* d_out, int out_size, void* d_ws, size_t ws_size,
                              hipStream_t stream)
{
    const float* q  = (const float*)d_in[0];
    const float* k  = (const float*)d_in[1];
    const float* v  = (const float*)d_in[2];
    const float* Wq = (const float*)d_in[4];
    const float* Wk = (const float*)d_in[5];
    const float* Wv = (const float*)d_in[6];
    const float* Wo = (const float*)d_in[7];

    const size_t NE = (size_t)4 * 16 * 2048 * 64;     // 8,388,608 elems / tensor
    const size_t WE = (size_t)1024 * 1024;
    unsigned short* Qh = (unsigned short*)d_ws;
    unsigned short* Kh = Qh + NE;
    unsigned short* Vt = Kh + NE;
    float* outp = (float*)d_out;
    dim3 blk(256);

    if (ws_size >= 6 * NE * 2 + 4 * WE * 2) {
        // ---- main path: bf16 pre-convert + dbuf stage-ahead GEMMs ----
        unsigned short* qb  = Vt + NE;      // Ctx aliases qb (dead after QKV gemm)
        unsigned short* kb  = qb + NE;
        unsigned short* vb  = kb + NE;
        unsigned short* wb  = vb + NE;
        unsigned short* Ctx = qb;
        conv_kernel<<<dim3(14336), blk, 0, stream>>>(q, k, v, Wq, Wk, Wv, Wo,
                                                     qb, kb, vb, wb);
        gemm2<0><<<dim3(768), dim3(512), 0, stream>>>(
            qb, kb, vb, wb, Qh, Kh, Vt, nullptr);
        attn_kernel<<<dim3(1024), dim3(512), 0, stream>>>(Qh, Kh, Vt, Ctx);
        gemm2<1><<<dim3(256), dim3(512), 0, stream>>>(
            Ctx, nullptr, nullptr, wb + 3 * WE, nullptr, nullptr, nullptr, outp);
    } else {
        // ---- fallback: convert in-GEMM (67.1 MB footprint) ----
        unsigned short* Ctx = Vt + NE;
        gemm_k<1, 1, 0><<<dim3(1536), blk, 0, stream>>>(
            q, k, v, Wq, Wk, Wv, Qh, Kh, Vt, nullptr);
        attn_kernel<<<dim3(1024), dim3(512), 0, stream>>>(Qh, Kh, Vt, Ctx);
        gemm_k<0, 1, 1><<<dim3(512), blk, 0, stream>>>(
            Ctx, nullptr, nullptr, Wo, nullptr, nullptr,
            nullptr, nullptr, nullptr, outp);
    }
}

// Round 5
// 200.093 us; speedup vs baseline: 2.7042x; 1.1255x over previous
//
#include <hip/hip_runtime.h>

// ---------- types ----------
typedef __attribute__((ext_vector_type(4))) float  f32x4;
typedef __attribute__((ext_vector_type(8))) short  s16x8;   // 8 bf16 (4 VGPRs)
typedef __attribute__((ext_vector_type(8))) unsigned short u16x8;
typedef __attribute__((ext_vector_type(4))) unsigned short u16x4;

static __device__ __forceinline__ unsigned short f2bf(float f) {
    unsigned int u = __builtin_bit_cast(unsigned int, f);
    u += 0x7fffu + ((u >> 16) & 1u);      // round-to-nearest-even
    return (unsigned short)(u >> 16);
}

static __device__ __forceinline__ unsigned int cvt_pk_bf16(float lo, float hi) {
    unsigned int r;
    asm("v_cvt_pk_bf16_f32 %0, %1, %2" : "=v"(r) : "v"(lo), "v"(hi));
    return r;
}

static __device__ __forceinline__ void gload16(const void* g, void* l) {
    __builtin_amdgcn_global_load_lds(
        (const __attribute__((address_space(1))) void*)g,
        (__attribute__((address_space(3))) void*)l, 16, 0, 0);
}

// =====================================================================
// fp32 -> bf16 convert pass: q,k,v + 4 weights. 2048 elems/block.
// =====================================================================
__global__ __launch_bounds__(256)
void conv_kernel(const float* __restrict__ q, const float* __restrict__ k,
                 const float* __restrict__ v,
                 const float* __restrict__ wq, const float* __restrict__ wk,
                 const float* __restrict__ wv, const float* __restrict__ wo,
                 unsigned short* __restrict__ qb, unsigned short* __restrict__ kb,
                 unsigned short* __restrict__ vb, unsigned short* __restrict__ wb)
{
    const int bid = blockIdx.x;
    const float* src; unsigned short* dst; int inner;
    if      (bid < 4096)  { src = q;  dst = qb; inner = bid; }
    else if (bid < 8192)  { src = k;  dst = kb; inner = bid - 4096; }
    else if (bid < 12288) { src = v;  dst = vb; inner = bid - 8192; }
    else {
        const int wseg = (bid - 12288) >> 9;
        src = wseg == 0 ? wq : wseg == 1 ? wk : wseg == 2 ? wv : wo;
        dst = wb + (size_t)wseg * 1048576;
        inner = (bid - 12288) & 511;
    }
    const size_t e0 = (size_t)inner * 2048 + threadIdx.x * 8;
    f32x4 a = *(const f32x4*)(src + e0);
    f32x4 b = *(const f32x4*)(src + e0 + 4);
    u16x8 o;
    #pragma unroll
    for (int i = 0; i < 4; ++i) { o[i] = f2bf(a[i]); o[i + 4] = f2bf(b[i]); }
    *(u16x8*)(dst + e0) = o;
}

// =====================================================================
// bf16 NT GEMM, 256x128 tile, BK=64, 8 waves, double-buffered LDS,
// stage-ahead: STAGE(next) -> ds_read+MFMA(cur) -> vmcnt(0) -> bar.
// EPI 0: fused QKV. grid 768. seg0->Qh*0.125 ; seg1->Kh ; seg2->Vt
// EPI 1: out proj. grid 256. Of fp32 [8192,1024].
// =====================================================================
template<int EPI>
__global__ __launch_bounds__(512)
void gemm2(const unsigned short* __restrict__ A0,
           const unsigned short* __restrict__ A1,
           const unsigned short* __restrict__ A2,
           const unsigned short* __restrict__ Bw,
           unsigned short* __restrict__ O0, unsigned short* __restrict__ O1,
           unsigned short* __restrict__ O2, float* __restrict__ Of)
{
    __shared__ unsigned short Asw[2][256 * 64];   // 64 KB
    __shared__ unsigned short Bsw[2][128 * 64];   // 32 KB

    const int tid  = threadIdx.x;
    const int lane = tid & 63;
    const int wave = tid >> 6;
    const int wr   = wave >> 1, wc = wave & 1;
    const int g    = lane >> 4, l16 = lane & 15;

    const int nblk = (EPI == 0) ? 768 : 256;
    const int cpx  = nblk >> 3;
    const int wg   = (blockIdx.x & 7) * cpx + (blockIdx.x >> 3);
    const int bx   = wg & 7;
    const int byt  = wg >> 3;
    const int seg  = (EPI == 0) ? (byt >> 5) : 0;
    const int byl  = (EPI == 0) ? (byt & 31) : byt;

    const unsigned short* Ap = (EPI == 0) ? (seg == 0 ? A0 : seg == 1 ? A1 : A2) : A0;
    const unsigned short* Arow = Ap + (size_t)(byl * 256) * 1024;
    const unsigned short* Brow = Bw + (size_t)seg * 1048576 + (size_t)(bx * 128) * 1024;

    f32x4 acc[4][4] = {};

    auto stage = [&](int buf, int kt) {
        #pragma unroll
        for (int j = 0; j < 4; ++j) {
            const int idx = j * 512 + tid;
            const int r   = idx >> 3;
            const int cl  = (tid & 7) ^ (r & 7);
            gload16(Arow + (size_t)r * 1024 + kt * 64 + cl * 8,
                    (char*)Asw[buf] + j * 8192 + wave * 1024);
        }
        #pragma unroll
        for (int j = 0; j < 2; ++j) {
            const int idx = j * 512 + tid;
            const int r   = idx >> 3;
            const int cl  = (tid & 7) ^ (r & 7);
            gload16(Brow + (size_t)r * 1024 + kt * 64 + cl * 8,
                    (char*)Bsw[buf] + j * 8192 + wave * 1024);
        }
    };

    stage(0, 0);
    asm volatile("s_waitcnt vmcnt(0)" ::: "memory");
    __builtin_amdgcn_s_barrier();

    int cur = 0;
    for (int kt = 0; kt < 16; ++kt) {
        if (kt < 15) stage(cur ^ 1, kt + 1);

        const char* Ab = (const char*)Asw[cur];
        const char* Bb = (const char*)Bsw[cur];
        #pragma unroll
        for (int ks = 0; ks < 2; ++ks) {
            s16x8 af[4], bf[4];
            #pragma unroll
            for (int mi = 0; mi < 4; ++mi) {
                const int row = wr * 64 + mi * 16 + l16;
                const int off = (row * 128 + g * 16 + ks * 64) ^ ((row & 7) << 4);
                af[mi] = __builtin_bit_cast(s16x8, *(const u16x8*)(Ab + off));
            }
            #pragma unroll
            for (int ni = 0; ni < 4; ++ni) {
                const int row = wc * 64 + ni * 16 + l16;
                const int off = (row * 128 + g * 16 + ks * 64) ^ ((row & 7) << 4);
                bf[ni] = __builtin_bit_cast(s16x8, *(const u16x8*)(Bb + off));
            }
            #pragma unroll
            for (int mi = 0; mi < 4; ++mi)
                #pragma unroll
                for (int ni = 0; ni < 4; ++ni)
                    acc[mi][ni] = __builtin_amdgcn_mfma_f32_16x16x32_bf16(
                        af[mi], bf[ni], acc[mi][ni], 0, 0, 0);
        }

        asm volatile("s_waitcnt vmcnt(0)" ::: "memory");
        __builtin_amdgcn_s_barrier();
        cur ^= 1;
    }

    #pragma unroll
    for (int mi = 0; mi < 4; ++mi) {
        #pragma unroll
        for (int ni = 0; ni < 4; ++ni) {
            const int gr0 = byl * 256 + wr * 64 + mi * 16 + g * 4;
            const int gc  = bx * 128 + wc * 64 + ni * 16 + l16;
            if (EPI == 0 && seg == 2) {
                const int b = gr0 >> 11, ll = gr0 & 2047;
                const int h = gc >> 6,  dh = gc & 63;
                u16x4 pk;
                #pragma unroll
                for (int rr = 0; rr < 4; ++rr) pk[rr] = f2bf(acc[mi][ni][rr]);
                *(u16x4*)(O2 + (size_t)((b * 16 + h) * 64 + dh) * 2048 + ll) = pk;
            } else {
                #pragma unroll
                for (int rr = 0; rr < 4; ++rr) {
                    const int gr = gr0 + rr;
                    float v = acc[mi][ni][rr];
                    if (EPI == 0) {
                        const int b = gr >> 11, ll = gr & 2047;
                        const int h = gc >> 6,  dh = gc & 63;
                        if (seg == 0) {
                            v *= 0.125f;
                            O0[(size_t)((b * 16 + h) * 2048 + ll) * 64 + dh] = f2bf(v);
                        } else {
                            O1[(size_t)((b * 16 + h) * 2048 + ll) * 64 + dh] = f2bf(v);
                        }
                    } else {
                        Of[(size_t)gr * 1024 + gc] = v;
                    }
                }
            }
        }
    }
}

// =====================================================================
// Fallback GEMM (fp32 inputs converted in-loop) — only used if ws too small.
// =====================================================================
template<int AM, int BM, int EPI>
__global__ __launch_bounds__(256)
void gemm_k(const void* __restrict__ A0, const void* __restrict__ A1,
            const void* __restrict__ A2,
            const void* __restrict__ B0, const void* __restrict__ B1,
            const void* __restrict__ B2,
            unsigned short* __restrict__ O0, unsigned short* __restrict__ O1,
            unsigned short* __restrict__ O2, float* __restrict__ Of)
{
    __shared__ unsigned short Asw[128 * 64];
    __shared__ unsigned short Bsw[128 * 64];

    const int tid  = threadIdx.x;
    const int lane = tid & 63;
    const int wave = tid >> 6;
    const int wr   = wave >> 1, wc = wave & 1;
    const int g    = lane >> 4, l16 = lane & 15;

    const int nper = (EPI == 0) ? 192 : 64;
    const int wg   = (blockIdx.x & 7) * nper + (blockIdx.x >> 3);
    const int bx   = wg & 7;
    const int by   = wg >> 3;
    const int seg  = (EPI == 0) ? (by >> 6) : 0;
    const int byl  = (EPI == 0) ? (by & 63) : by;

    const void* Ap = seg == 0 ? A0 : seg == 1 ? A1 : A2;
    const void* Bp = seg == 0 ? B0 : seg == 1 ? B1 : B2;

    f32x4 acc[4][4] = {};

    for (int kt = 0; kt < 16; ++kt) {
        __syncthreads();
        if (AM == 0) {
            #pragma unroll
            for (int j = 0; j < 4; ++j) {
                const int idx = j * 256 + tid;
                const int r   = idx >> 3;
                const int cl  = (tid & 7) ^ (r & 7);
                gload16((const unsigned short*)Ap + (size_t)(byl * 128 + r) * 1024 + kt * 64 + cl * 8,
                        (char*)Asw + j * 4096 + wave * 1024);
            }
        } else {
            #pragma unroll
            for (int j = 0; j < 4; ++j) {
                const int idx = j * 256 + tid;
                const int r = idx >> 3, c = tid & 7;
                const float* src = (const float*)Ap + (size_t)(byl * 128 + r) * 1024 + kt * 64 + c * 8;
                f32x4 a = *(const f32x4*)src;
                f32x4 b = *(const f32x4*)(src + 4);
                u16x8 w;
                #pragma unroll
                for (int i = 0; i < 4; ++i) { w[i] = f2bf(a[i]); w[i + 4] = f2bf(b[i]); }
                *(u16x8*)((char*)Asw + ((r * 128 + c * 16) ^ ((r & 7) << 4))) = w;
            }
        }
        if (BM == 0) {
            #pragma unroll
            for (int j = 0; j < 4; ++j) {
                const int idx = j * 256 + tid;
                const int r   = idx >> 3;
                const int cl  = (tid & 7) ^ (r & 7);
                gload16((const unsigned short*)Bp + (size_t)(bx * 128 + r) * 1024 + kt * 64 + cl * 8,
                        (char*)Bsw + j * 4096 + wave * 1024);
            }
        } else {
            #pragma unroll
            for (int j = 0; j < 4; ++j) {
                const int idx = j * 256 + tid;
                const int r = idx >> 3, c = tid & 7;
                const float* src = (const float*)Bp + (size_t)(bx * 128 + r) * 1024 + kt * 64 + c * 8;
                f32x4 a = *(const f32x4*)src;
                f32x4 b = *(const f32x4*)(src + 4);
                u16x8 w;
                #pragma unroll
                for (int i = 0; i < 4; ++i) { w[i] = f2bf(a[i]); w[i + 4] = f2bf(b[i]); }
                *(u16x8*)((char*)Bsw + ((r * 128 + c * 16) ^ ((r & 7) << 4))) = w;
            }
        }
        __syncthreads();

        #pragma unroll
        for (int ks = 0; ks < 2; ++ks) {
            s16x8 af[4], bf[4];
            #pragma unroll
            for (int mi = 0; mi < 4; ++mi) {
                const int row = wr * 64 + mi * 16 + l16;
                const int off = (row * 128 + g * 16 + ks * 64) ^ ((row & 7) << 4);
                af[mi] = __builtin_bit_cast(s16x8, *(const u16x8*)((const char*)Asw + off));
            }
            #pragma unroll
            for (int ni = 0; ni < 4; ++ni) {
                const int row = wc * 64 + ni * 16 + l16;
                const int off = (row * 128 + g * 16 + ks * 64) ^ ((row & 7) << 4);
                bf[ni] = __builtin_bit_cast(s16x8, *(const u16x8*)((const char*)Bsw + off));
            }
            #pragma unroll
            for (int mi = 0; mi < 4; ++mi)
                #pragma unroll
                for (int ni = 0; ni < 4; ++ni)
                    acc[mi][ni] = __builtin_amdgcn_mfma_f32_16x16x32_bf16(
                        af[mi], bf[ni], acc[mi][ni], 0, 0, 0);
        }
    }

    #pragma unroll
    for (int mi = 0; mi < 4; ++mi) {
        #pragma unroll
        for (int ni = 0; ni < 4; ++ni) {
            #pragma unroll
            for (int rr = 0; rr < 4; ++rr) {
                const int gr = byl * 128 + wr * 64 + mi * 16 + g * 4 + rr;
                const int gc = bx * 128 + wc * 64 + ni * 16 + l16;
                float v = acc[mi][ni][rr];
                if (EPI == 0) {
                    const int b = gr >> 11, ll = gr & 2047, h = gc >> 6, dh = gc & 63;
                    if (seg == 0) {
                        v *= 0.125f;
                        O0[(size_t)((b * 16 + h) * 2048 + ll) * 64 + dh] = f2bf(v);
                    } else if (seg == 1) {
                        O1[(size_t)((b * 16 + h) * 2048 + ll) * 64 + dh] = f2bf(v);
                    } else {
                        O2[(size_t)((b * 16 + h) * 64 + dh) * 2048 + ll] = f2bf(v);
                    }
                } else {
                    Of[(size_t)gr * 1024 + gc] = v;
                }
            }
        }
    }
}

// =====================================================================
// Flash-style causal attention, double-buffered KV.
// Swapped QK^T (S^T = mfma(K,Q)) -> per-lane row softmax (q = l16),
// defer-max (THR=8), cvt_pk P->bf16, b64 P writes.
// =====================================================================
__global__ __launch_bounds__(512)
void attn_kernel(const unsigned short* __restrict__ Qh,
                 const unsigned short* __restrict__ Kh,
                 const unsigned short* __restrict__ Vt,
                 unsigned short* __restrict__ Ctx)
{
    __shared__ unsigned short Ksw[2][64 * 64];
    __shared__ unsigned short Vsw[2][64 * 64];
    __shared__ unsigned short Psw[8][16 * 64];

    const int tid  = threadIdx.x;
    const int lane = tid & 63;
    const int wave = tid >> 6;
    const int g    = lane >> 4, l16 = lane & 15;
    const int qb   = 15 - (int)(blockIdx.x >> 6);
    const int bh   = blockIdx.x & 63;
    const int b    = bh >> 4, h = bh & 15;
    const int qrow0 = qb * 128 + wave * 16;
    const int ntile = 2 * qb + 2;

    const int sr = tid >> 3, sc = tid & 7;
    const int soff = (sr * 128 + sc * 16) ^ ((sr & 7) << 4);
    const unsigned short* kbase = Kh + ((size_t)bh * 2048 + sr) * 64 + sc * 8;
    const unsigned short* vbase = Vt + ((size_t)bh * 64 + sr) * 2048 + sc * 8;

    s16x8 qf[2];
    {
        const unsigned short* qp = Qh + ((size_t)bh * 2048 + qrow0 + l16) * 64 + g * 8;
        qf[0] = __builtin_bit_cast(s16x8, *(const u16x8*)qp);
        qf[1] = __builtin_bit_cast(s16x8, *(const u16x8*)(qp + 32));
    }

    f32x4 o[4] = {};
    float m = -3.0e38f, l = 0.f;   // per-lane row state: q = l16

    *(u16x8*)((char*)Ksw[0] + soff) = *(const u16x8*)kbase;
    *(u16x8*)((char*)Vsw[0] + soff) = *(const u16x8*)vbase;
    __syncthreads();

    int cur = 0;
    for (int t = 0; t < ntile; ++t) {
        const int kv0 = t * 64;

        u16x8 kn, vn;
        const bool hn = (t + 1 < ntile);
        if (hn) {
            kn = *(const u16x8*)(kbase + (size_t)(kv0 + 64) * 64);
            vn = *(const u16x8*)(vbase + (kv0 + 64));
        }

        if (kv0 <= qrow0 + 15) {
            const char* Kb = (const char*)Ksw[cur];
            const char* Vb = (const char*)Vsw[cur];

            // ---- S^T = K Q^T : st[nt][rr] = S[kv = kv0+nt*16+g*4+rr][q = qrow0+l16]
            f32x4 st[4] = {};
            __builtin_amdgcn_s_setprio(1);
            #pragma unroll
            for (int nt = 0; nt < 4; ++nt) {
                #pragma unroll
                for (int ks = 0; ks < 2; ++ks) {
                    const int row = nt * 16 + l16;
                    const int off = (row * 128 + g * 16 + ks * 64) ^ ((row & 7) << 4);
                    s16x8 kf = __builtin_bit_cast(s16x8, *(const u16x8*)(Kb + off));
                    st[nt] = __builtin_amdgcn_mfma_f32_16x16x32_bf16(kf, qf[ks], st[nt], 0, 0, 0);
                }
            }
            __builtin_amdgcn_s_setprio(0);

            // ---- causal mask (diagonal tiles only) ----
            if (kv0 + 63 > qrow0) {
                const int q_g = qrow0 + l16;
                #pragma unroll
                for (int nt = 0; nt < 4; ++nt)
                    #pragma unroll
                    for (int rr = 0; rr < 4; ++rr) {
                        const int kv_g = kv0 + nt * 16 + g * 4 + rr;
                        if (kv_g > q_g) st[nt][rr] = -3.0e38f;
                    }
            }

            // ---- per-lane row max, reduce across g groups ----
            float pmax = fmaxf(
                fmaxf(fmaxf(fmaxf(st[0][0], st[0][1]), fmaxf(st[0][2], st[0][3])),
                      fmaxf(fmaxf(st[1][0], st[1][1]), fmaxf(st[1][2], st[1][3]))),
                fmaxf(fmaxf(fmaxf(st[2][0], st[2][1]), fmaxf(st[2][2], st[2][3])),
                      fmaxf(fmaxf(st[3][0], st[3][1]), fmaxf(st[3][2], st[3][3]))));
            pmax = fmaxf(pmax, __shfl_xor(pmax, 16));
            pmax = fmaxf(pmax, __shfl_xor(pmax, 32));

            if (__all(pmax <= m + 8.0f)) {
                // ---- defer-max: no rescale, keep old m ----
                float r0 = 0.f;
                #pragma unroll
                for (int nt = 0; nt < 4; ++nt)
                    #pragma unroll
                    for (int rr = 0; rr < 4; ++rr) {
                        const float p = __expf(st[nt][rr] - m);
                        st[nt][rr] = p;
                        r0 += p;
                    }
                r0 += __shfl_xor(r0, 16);
                r0 += __shfl_xor(r0, 32);
                l += r0;
            } else {
                const float mn = fmaxf(m, pmax);
                const float scf = __expf(m - mn);
                m = mn;
                float r0 = 0.f;
                #pragma unroll
                for (int nt = 0; nt < 4; ++nt)
                    #pragma unroll
                    for (int rr = 0; rr < 4; ++rr) {
                        const float p = __expf(st[nt][rr] - mn);
                        st[nt][rr] = p;
                        r0 += p;
                    }
                r0 += __shfl_xor(r0, 16);
                r0 += __shfl_xor(r0, 32);
                l = l * scf + r0;
                // rescale o: o rows are q = g*4+rr -> fetch sc from lane g*4+rr
                float sc4[4];
                #pragma unroll
                for (int rr = 0; rr < 4; ++rr) sc4[rr] = __shfl(scf, g * 4 + rr);
                #pragma unroll
                for (int nt = 0; nt < 4; ++nt)
                    #pragma unroll
                    for (int rr = 0; rr < 4; ++rr)
                        o[nt][rr] *= sc4[rr];
            }

            // ---- P -> per-wave LDS: pack pairs (consecutive kv) via cvt_pk ----
            unsigned short* Pw = Psw[wave];
            #pragma unroll
            for (int nt = 0; nt < 4; ++nt) {
                const unsigned int w0 = cvt_pk_bf16(st[nt][0], st[nt][1]);
                const unsigned int w1 = cvt_pk_bf16(st[nt][2], st[nt][3]);
                const int off = (l16 * 128 + nt * 32 + g * 8) ^ ((l16 & 7) << 4);
                const unsigned long long dw = ((unsigned long long)w1 << 32) | w0;
                *(unsigned long long*)((char*)Pw + off) = dw;
            }
            // wave-private LDS: in-order per-wave DS pipe, no barrier

            __builtin_amdgcn_s_setprio(1);
            #pragma unroll
            for (int ks = 0; ks < 2; ++ks) {
                const int offp = (l16 * 128 + g * 16 + ks * 64) ^ ((l16 & 7) << 4);
                s16x8 pf = __builtin_bit_cast(s16x8, *(const u16x8*)((const char*)Pw + offp));
                #pragma unroll
                for (int nt = 0; nt < 4; ++nt) {
                    const int row = nt * 16 + l16;
                    const int off = (row * 128 + g * 16 + ks * 64) ^ ((row & 7) << 4);
                    s16x8 vf = __builtin_bit_cast(s16x8, *(const u16x8*)(Vb + off));
                    o[nt] = __builtin_amdgcn_mfma_f32_16x16x32_bf16(pf, vf, o[nt], 0, 0, 0);
                }
            }
            __builtin_amdgcn_s_setprio(0);
        }

        if (hn) {
            *(u16x8*)((char*)Ksw[cur ^ 1] + soff) = kn;
            *(u16x8*)((char*)Vsw[cur ^ 1] + soff) = vn;
        }
        __syncthreads();
        cur ^= 1;
    }

    // ---- epilogue: o rows q = g*4+rr; l lives on lane l16 = that row ----
    #pragma unroll
    for (int rr = 0; rr < 4; ++rr) {
        const float lq = __shfl(l, g * 4 + rr);
        const float inv = 1.0f / lq;
        const int q_g = qrow0 + g * 4 + rr;
        #pragma unroll
        for (int nt = 0; nt < 4; ++nt) {
            const int d = nt * 16 + l16;
            Ctx[((size_t)b * 2048 + q_g) * 1024 + h * 64 + d] = f2bf(o[nt][rr] * inv);
        }
    }
}

// =====================================================================
extern "C" void kernel_launch(void* const* d_in, const int* in_sizes, int n_in,
                              void* d_out, int out_size, void* d_ws, size_t ws_size,
                              hipStream_t stream)
{
    const float* q  = (const float*)d_in[0];
    const float* k  = (const float*)d_in[1];
    const float* v  = (const float*)d_in[2];
    const float* Wq = (const float*)d_in[4];
    const float* Wk = (const float*)d_in[5];
    const float* Wv = (const float*)d_in[6];
    const float* Wo = (const float*)d_in[7];

    const size_t NE = (size_t)4 * 16 * 2048 * 64;
    const size_t WE = (size_t)1024 * 1024;
    unsigned short* Qh = (unsigned short*)d_ws;
    unsigned short* Kh = Qh + NE;
    unsigned short* Vt = Kh + NE;
    float* outp = (float*)d_out;
    dim3 blk(256);

    if (ws_size >= 6 * NE * 2 + 4 * WE * 2) {
        unsigned short* qb  = Vt + NE;
        unsigned short* kb  = qb + NE;
        unsigned short* vb  = kb + NE;
        unsigned short* wb  = vb + NE;
        unsigned short* Ctx = qb;
        conv_kernel<<<dim3(14336), blk, 0, stream>>>(q, k, v, Wq, Wk, Wv, Wo,
                                                     qb, kb, vb, wb);
        gemm2<0><<<dim3(768), dim3(512), 0, stream>>>(
            qb, kb, vb, wb, Qh, Kh, Vt, nullptr);
        attn_kernel<<<dim3(1024), dim3(512), 0, stream>>>(Qh, Kh, Vt, Ctx);
        gemm2<1><<<dim3(256), dim3(512), 0, stream>>>(
            Ctx, nullptr, nullptr, wb + 3 * WE, nullptr, nullptr, nullptr, outp);
    } else {
        unsigned short* Ctx = Vt + NE;
        gemm_k<1, 1, 0><<<dim3(1536), blk, 0, stream>>>(
            q, k, v, Wq, Wk, Wv, Qh, Kh, Vt, nullptr);
        attn_kernel<<<dim3(1024), dim3(512), 0, stream>>>(Qh, Kh, Vt, Ctx);
        gemm_k<0, 1, 1><<<dim3(512), blk, 0, stream>>>(
            Ctx, nullptr, nullptr, Wo, nullptr, nullptr,
            nullptr, nullptr, nullptr, outp);
    }
}

// Round 6
// 192.768 us; speedup vs baseline: 2.8070x; 1.0380x over previous
//
#include <hip/hip_runtime.h>

// ---------- types ----------
typedef __attribute__((ext_vector_type(4))) float  f32x4;
typedef __attribute__((ext_vector_type(8))) short  s16x8;   // 8 bf16 (4 VGPRs)
typedef __attribute__((ext_vector_type(8))) unsigned short u16x8;
typedef __attribute__((ext_vector_type(4))) unsigned short u16x4;

static __device__ __forceinline__ unsigned short f2bf(float f) {
    unsigned int u = __builtin_bit_cast(unsigned int, f);
    u += 0x7fffu + ((u >> 16) & 1u);      // round-to-nearest-even
    return (unsigned short)(u >> 16);
}

static __device__ __forceinline__ unsigned int cvt_pk_bf16(float lo, float hi) {
    unsigned int r;
    asm("v_cvt_pk_bf16_f32 %0, %1, %2" : "=v"(r) : "v"(lo), "v"(hi));
    return r;
}

static __device__ __forceinline__ void gload16(const void* g, void* l) {
    __builtin_amdgcn_global_load_lds(
        (const __attribute__((address_space(1))) void*)g,
        (__attribute__((address_space(3))) void*)l, 16, 0, 0);
}

// =====================================================================
// fp32 -> bf16 convert pass: q,k,v + 4 weights. 2048 elems/block.
// =====================================================================
__global__ __launch_bounds__(256)
void conv_kernel(const float* __restrict__ q, const float* __restrict__ k,
                 const float* __restrict__ v,
                 const float* __restrict__ wq, const float* __restrict__ wk,
                 const float* __restrict__ wv, const float* __restrict__ wo,
                 unsigned short* __restrict__ qb, unsigned short* __restrict__ kb,
                 unsigned short* __restrict__ vb, unsigned short* __restrict__ wb)
{
    const int bid = blockIdx.x;
    const float* src; unsigned short* dst; int inner;
    if      (bid < 4096)  { src = q;  dst = qb; inner = bid; }
    else if (bid < 8192)  { src = k;  dst = kb; inner = bid - 4096; }
    else if (bid < 12288) { src = v;  dst = vb; inner = bid - 8192; }
    else {
        const int wseg = (bid - 12288) >> 9;
        src = wseg == 0 ? wq : wseg == 1 ? wk : wseg == 2 ? wv : wo;
        dst = wb + (size_t)wseg * 1048576;
        inner = (bid - 12288) & 511;
    }
    const size_t e0 = (size_t)inner * 2048 + threadIdx.x * 8;
    f32x4 a = *(const f32x4*)(src + e0);
    f32x4 b = *(const f32x4*)(src + e0 + 4);
    u16x8 o;
    #pragma unroll
    for (int i = 0; i < 4; ++i) { o[i] = f2bf(a[i]); o[i + 4] = f2bf(b[i]); }
    *(u16x8*)(dst + e0) = o;
}

// =====================================================================
// bf16 NT GEMM, 256x128 tile, BK=64, 8 waves (4x2), ring-3 LDS (144 KB),
// counted vmcnt(6): stage(t+2) -> compute(t) -> vmcnt(6) -> barrier.
// Tile t+1's loads were issued a FULL iteration before they're needed.
// EPI 0: fused QKV. grid 768. seg0->Qh*0.125 ; seg1->Kh ; seg2->Vt
// EPI 1: out proj. grid 256. Of fp32 [8192,1024].
// =====================================================================
template<int EPI>
__global__ __launch_bounds__(512)
void gemm3(const unsigned short* __restrict__ A0,
           const unsigned short* __restrict__ A1,
           const unsigned short* __restrict__ A2,
           const unsigned short* __restrict__ Bw,
           unsigned short* __restrict__ O0, unsigned short* __restrict__ O1,
           unsigned short* __restrict__ O2, float* __restrict__ Of)
{
    __shared__ unsigned short Asw[3][256 * 64];   // 96 KB
    __shared__ unsigned short Bsw[3][128 * 64];   // 48 KB

    const int tid  = threadIdx.x;
    const int lane = tid & 63;
    const int wave = tid >> 6;
    const int wr   = wave >> 1, wc = wave & 1;    // 4 x 2 waves, 64x64 each
    const int g    = lane >> 4, l16 = lane & 15;

    const int nblk = (EPI == 0) ? 768 : 256;
    const int cpx  = nblk >> 3;
    const int wg   = (blockIdx.x & 7) * cpx + (blockIdx.x >> 3);  // bijective XCD swizzle
    const int bx   = wg & 7;
    const int byt  = wg >> 3;
    const int seg  = (EPI == 0) ? (byt >> 5) : 0;
    const int byl  = (EPI == 0) ? (byt & 31) : byt;

    const unsigned short* Ap = (EPI == 0) ? (seg == 0 ? A0 : seg == 1 ? A1 : A2) : A0;
    const unsigned short* Arow = Ap + (size_t)(byl * 256) * 1024;
    const unsigned short* Brow = Bw + (size_t)seg * 1048576 + (size_t)(bx * 128) * 1024;

    f32x4 acc[4][4] = {};

    // stage one K-tile (256x64 A + 128x64 B) into ring buffer `buf`.
    // linear LDS dest (gload_lds), inverse-swizzled global source (rule 21).
    // 6 VMEM instructions per thread per tile (4 A + 2 B) — vmcnt counting
    // relies on this fixed count.
    auto stage = [&](int buf, int kt) {
        #pragma unroll
        for (int j = 0; j < 4; ++j) {
            const int idx = j * 512 + tid;
            const int r   = idx >> 3;
            const int cl  = (tid & 7) ^ (r & 7);
            gload16(Arow + (size_t)r * 1024 + kt * 64 + cl * 8,
                    (char*)Asw[buf] + j * 8192 + wave * 1024);
        }
        #pragma unroll
        for (int j = 0; j < 2; ++j) {
            const int idx = j * 512 + tid;
            const int r   = idx >> 3;
            const int cl  = (tid & 7) ^ (r & 7);
            gload16(Brow + (size_t)r * 1024 + kt * 64 + cl * 8,
                    (char*)Bsw[buf] + j * 8192 + wave * 1024);
        }
    };

    // prologue: 2 tiles in flight; wait for tile 0 only (6 newest = tile 1).
    stage(0, 0);
    stage(1, 1);
    asm volatile("s_waitcnt vmcnt(6)" ::: "memory");
    __builtin_amdgcn_s_barrier();

    for (int kt = 0; kt < 16; ++kt) {
        if (kt + 2 < 16) stage((kt + 2) % 3, kt + 2);   // 2 tiles ahead

        const char* Ab = (const char*)Asw[kt % 3];
        const char* Bb = (const char*)Bsw[kt % 3];
        #pragma unroll
        for (int ks = 0; ks < 2; ++ks) {
            s16x8 af[4], bf[4];
            #pragma unroll
            for (int mi = 0; mi < 4; ++mi) {
                const int row = wr * 64 + mi * 16 + l16;
                const int off = (row * 128 + g * 16 + ks * 64) ^ ((row & 7) << 4);
                af[mi] = __builtin_bit_cast(s16x8, *(const u16x8*)(Ab + off));
            }
            #pragma unroll
            for (int ni = 0; ni < 4; ++ni) {
                const int row = wc * 64 + ni * 16 + l16;
                const int off = (row * 128 + g * 16 + ks * 64) ^ ((row & 7) << 4);
                bf[ni] = __builtin_bit_cast(s16x8, *(const u16x8*)(Bb + off));
            }
            __builtin_amdgcn_s_setprio(1);
            #pragma unroll
            for (int mi = 0; mi < 4; ++mi)
                #pragma unroll
                for (int ni = 0; ni < 4; ++ni)
                    acc[mi][ni] = __builtin_amdgcn_mfma_f32_16x16x32_bf16(
                        af[mi], bf[ni], acc[mi][ni], 0, 0, 0);
            __builtin_amdgcn_s_setprio(0);
        }

        // counted wait: tile kt+1 landed; tile kt+2 (newest 6) stays in flight.
        if (kt + 2 < 16) asm volatile("s_waitcnt vmcnt(6)" ::: "memory");
        else             asm volatile("s_waitcnt vmcnt(0)" ::: "memory");
        __builtin_amdgcn_s_barrier();
    }

    // ---- epilogue ----
    #pragma unroll
    for (int mi = 0; mi < 4; ++mi) {
        #pragma unroll
        for (int ni = 0; ni < 4; ++ni) {
            const int gr0 = byl * 256 + wr * 64 + mi * 16 + g * 4;
            const int gc  = bx * 128 + wc * 64 + ni * 16 + l16;
            if (EPI == 0 && seg == 2) {
                const int b = gr0 >> 11, ll = gr0 & 2047;
                const int h = gc >> 6,  dh = gc & 63;
                u16x4 pk;
                #pragma unroll
                for (int rr = 0; rr < 4; ++rr) pk[rr] = f2bf(acc[mi][ni][rr]);
                *(u16x4*)(O2 + (size_t)((b * 16 + h) * 64 + dh) * 2048 + ll) = pk;
            } else {
                #pragma unroll
                for (int rr = 0; rr < 4; ++rr) {
                    const int gr = gr0 + rr;
                    float v = acc[mi][ni][rr];
                    if (EPI == 0) {
                        const int b = gr >> 11, ll = gr & 2047;
                        const int h = gc >> 6,  dh = gc & 63;
                        if (seg == 0) {
                            v *= 0.125f;
                            O0[(size_t)((b * 16 + h) * 2048 + ll) * 64 + dh] = f2bf(v);
                        } else {
                            O1[(size_t)((b * 16 + h) * 2048 + ll) * 64 + dh] = f2bf(v);
                        }
                    } else {
                        Of[(size_t)gr * 1024 + gc] = v;
                    }
                }
            }
        }
    }
}

// =====================================================================
// Fallback GEMM (fp32 inputs converted in-loop) — only used if ws too small.
// =====================================================================
template<int AM, int BM, int EPI>
__global__ __launch_bounds__(256)
void gemm_k(const void* __restrict__ A0, const void* __restrict__ A1,
            const void* __restrict__ A2,
            const void* __restrict__ B0, const void* __restrict__ B1,
            const void* __restrict__ B2,
            unsigned short* __restrict__ O0, unsigned short* __restrict__ O1,
            unsigned short* __restrict__ O2, float* __restrict__ Of)
{
    __shared__ unsigned short Asw[128 * 64];
    __shared__ unsigned short Bsw[128 * 64];

    const int tid  = threadIdx.x;
    const int lane = tid & 63;
    const int wave = tid >> 6;
    const int wr   = wave >> 1, wc = wave & 1;
    const int g    = lane >> 4, l16 = lane & 15;

    const int nper = (EPI == 0) ? 192 : 64;
    const int wg   = (blockIdx.x & 7) * nper + (blockIdx.x >> 3);
    const int bx   = wg & 7;
    const int by   = wg >> 3;
    const int seg  = (EPI == 0) ? (by >> 6) : 0;
    const int byl  = (EPI == 0) ? (by & 63) : by;

    const void* Ap = seg == 0 ? A0 : seg == 1 ? A1 : A2;
    const void* Bp = seg == 0 ? B0 : seg == 1 ? B1 : B2;

    f32x4 acc[4][4] = {};

    for (int kt = 0; kt < 16; ++kt) {
        __syncthreads();
        if (AM == 0) {
            #pragma unroll
            for (int j = 0; j < 4; ++j) {
                const int idx = j * 256 + tid;
                const int r   = idx >> 3;
                const int cl  = (tid & 7) ^ (r & 7);
                gload16((const unsigned short*)Ap + (size_t)(byl * 128 + r) * 1024 + kt * 64 + cl * 8,
                        (char*)Asw + j * 4096 + wave * 1024);
            }
        } else {
            #pragma unroll
            for (int j = 0; j < 4; ++j) {
                const int idx = j * 256 + tid;
                const int r = idx >> 3, c = tid & 7;
                const float* src = (const float*)Ap + (size_t)(byl * 128 + r) * 1024 + kt * 64 + c * 8;
                f32x4 a = *(const f32x4*)src;
                f32x4 b = *(const f32x4*)(src + 4);
                u16x8 w;
                #pragma unroll
                for (int i = 0; i < 4; ++i) { w[i] = f2bf(a[i]); w[i + 4] = f2bf(b[i]); }
                *(u16x8*)((char*)Asw + ((r * 128 + c * 16) ^ ((r & 7) << 4))) = w;
            }
        }
        if (BM == 0) {
            #pragma unroll
            for (int j = 0; j < 4; ++j) {
                const int idx = j * 256 + tid;
                const int r   = idx >> 3;
                const int cl  = (tid & 7) ^ (r & 7);
                gload16((const unsigned short*)Bp + (size_t)(bx * 128 + r) * 1024 + kt * 64 + cl * 8,
                        (char*)Bsw + j * 4096 + wave * 1024);
            }
        } else {
            #pragma unroll
            for (int j = 0; j < 4; ++j) {
                const int idx = j * 256 + tid;
                const int r = idx >> 3, c = tid & 7;
                const float* src = (const float*)Bp + (size_t)(bx * 128 + r) * 1024 + kt * 64 + c * 8;
                f32x4 a = *(const f32x4*)src;
                f32x4 b = *(const f32x4*)(src + 4);
                u16x8 w;
                #pragma unroll
                for (int i = 0; i < 4; ++i) { w[i] = f2bf(a[i]); w[i + 4] = f2bf(b[i]); }
                *(u16x8*)((char*)Bsw + ((r * 128 + c * 16) ^ ((r & 7) << 4))) = w;
            }
        }
        __syncthreads();

        #pragma unroll
        for (int ks = 0; ks < 2; ++ks) {
            s16x8 af[4], bf[4];
            #pragma unroll
            for (int mi = 0; mi < 4; ++mi) {
                const int row = wr * 64 + mi * 16 + l16;
                const int off = (row * 128 + g * 16 + ks * 64) ^ ((row & 7) << 4);
                af[mi] = __builtin_bit_cast(s16x8, *(const u16x8*)((const char*)Asw + off));
            }
            #pragma unroll
            for (int ni = 0; ni < 4; ++ni) {
                const int row = wc * 64 + ni * 16 + l16;
                const int off = (row * 128 + g * 16 + ks * 64) ^ ((row & 7) << 4);
                bf[ni] = __builtin_bit_cast(s16x8, *(const u16x8*)((const char*)Bsw + off));
            }
            #pragma unroll
            for (int mi = 0; mi < 4; ++mi)
                #pragma unroll
                for (int ni = 0; ni < 4; ++ni)
                    acc[mi][ni] = __builtin_amdgcn_mfma_f32_16x16x32_bf16(
                        af[mi], bf[ni], acc[mi][ni], 0, 0, 0);
        }
    }

    #pragma unroll
    for (int mi = 0; mi < 4; ++mi) {
        #pragma unroll
        for (int ni = 0; ni < 4; ++ni) {
            #pragma unroll
            for (int rr = 0; rr < 4; ++rr) {
                const int gr = byl * 128 + wr * 64 + mi * 16 + g * 4 + rr;
                const int gc = bx * 128 + wc * 64 + ni * 16 + l16;
                float v = acc[mi][ni][rr];
                if (EPI == 0) {
                    const int b = gr >> 11, ll = gr & 2047, h = gc >> 6, dh = gc & 63;
                    if (seg == 0) {
                        v *= 0.125f;
                        O0[(size_t)((b * 16 + h) * 2048 + ll) * 64 + dh] = f2bf(v);
                    } else if (seg == 1) {
                        O1[(size_t)((b * 16 + h) * 2048 + ll) * 64 + dh] = f2bf(v);
                    } else {
                        O2[(size_t)((b * 16 + h) * 64 + dh) * 2048 + ll] = f2bf(v);
                    }
                } else {
                    Of[(size_t)gr * 1024 + gc] = v;
                }
            }
        }
    }
}

// =====================================================================
// Flash-style causal attention, double-buffered KV.
// Swapped QK^T (S^T = mfma(K,Q)) -> per-lane row softmax (q = l16),
// defer-max (THR=8), cvt_pk P->bf16, b64 P writes.  (unchanged from R5)
// =====================================================================
__global__ __launch_bounds__(512)
void attn_kernel(const unsigned short* __restrict__ Qh,
                 const unsigned short* __restrict__ Kh,
                 const unsigned short* __restrict__ Vt,
                 unsigned short* __restrict__ Ctx)
{
    __shared__ unsigned short Ksw[2][64 * 64];
    __shared__ unsigned short Vsw[2][64 * 64];
    __shared__ unsigned short Psw[8][16 * 64];

    const int tid  = threadIdx.x;
    const int lane = tid & 63;
    const int wave = tid >> 6;
    const int g    = lane >> 4, l16 = lane & 15;
    const int qb   = 15 - (int)(blockIdx.x >> 6);
    const int bh   = blockIdx.x & 63;
    const int b    = bh >> 4, h = bh & 15;
    const int qrow0 = qb * 128 + wave * 16;
    const int ntile = 2 * qb + 2;

    const int sr = tid >> 3, sc = tid & 7;
    const int soff = (sr * 128 + sc * 16) ^ ((sr & 7) << 4);
    const unsigned short* kbase = Kh + ((size_t)bh * 2048 + sr) * 64 + sc * 8;
    const unsigned short* vbase = Vt + ((size_t)bh * 64 + sr) * 2048 + sc * 8;

    s16x8 qf[2];
    {
        const unsigned short* qp = Qh + ((size_t)bh * 2048 + qrow0 + l16) * 64 + g * 8;
        qf[0] = __builtin_bit_cast(s16x8, *(const u16x8*)qp);
        qf[1] = __builtin_bit_cast(s16x8, *(const u16x8*)(qp + 32));
    }

    f32x4 o[4] = {};
    float m = -3.0e38f, l = 0.f;   // per-lane row state: q = l16

    *(u16x8*)((char*)Ksw[0] + soff) = *(const u16x8*)kbase;
    *(u16x8*)((char*)Vsw[0] + soff) = *(const u16x8*)vbase;
    __syncthreads();

    int cur = 0;
    for (int t = 0; t < ntile; ++t) {
        const int kv0 = t * 64;

        u16x8 kn, vn;
        const bool hn = (t + 1 < ntile);
        if (hn) {
            kn = *(const u16x8*)(kbase + (size_t)(kv0 + 64) * 64);
            vn = *(const u16x8*)(vbase + (kv0 + 64));
        }

        if (kv0 <= qrow0 + 15) {
            const char* Kb = (const char*)Ksw[cur];
            const char* Vb = (const char*)Vsw[cur];

            // ---- S^T = K Q^T : st[nt][rr] = S[kv = kv0+nt*16+g*4+rr][q = qrow0+l16]
            f32x4 st[4] = {};
            __builtin_amdgcn_s_setprio(1);
            #pragma unroll
            for (int nt = 0; nt < 4; ++nt) {
                #pragma unroll
                for (int ks = 0; ks < 2; ++ks) {
                    const int row = nt * 16 + l16;
                    const int off = (row * 128 + g * 16 + ks * 64) ^ ((row & 7) << 4);
                    s16x8 kf = __builtin_bit_cast(s16x8, *(const u16x8*)(Kb + off));
                    st[nt] = __builtin_amdgcn_mfma_f32_16x16x32_bf16(kf, qf[ks], st[nt], 0, 0, 0);
                }
            }
            __builtin_amdgcn_s_setprio(0);

            // ---- causal mask (diagonal tiles only) ----
            if (kv0 + 63 > qrow0) {
                const int q_g = qrow0 + l16;
                #pragma unroll
                for (int nt = 0; nt < 4; ++nt)
                    #pragma unroll
                    for (int rr = 0; rr < 4; ++rr) {
                        const int kv_g = kv0 + nt * 16 + g * 4 + rr;
                        if (kv_g > q_g) st[nt][rr] = -3.0e38f;
                    }
            }

            // ---- per-lane row max, reduce across g groups ----
            float pmax = fmaxf(
                fmaxf(fmaxf(fmaxf(st[0][0], st[0][1]), fmaxf(st[0][2], st[0][3])),
                      fmaxf(fmaxf(st[1][0], st[1][1]), fmaxf(st[1][2], st[1][3]))),
                fmaxf(fmaxf(fmaxf(st[2][0], st[2][1]), fmaxf(st[2][2], st[2][3])),
                      fmaxf(fmaxf(st[3][0], st[3][1]), fmaxf(st[3][2], st[3][3]))));
            pmax = fmaxf(pmax, __shfl_xor(pmax, 16));
            pmax = fmaxf(pmax, __shfl_xor(pmax, 32));

            if (__all(pmax <= m + 8.0f)) {
                float r0 = 0.f;
                #pragma unroll
                for (int nt = 0; nt < 4; ++nt)
                    #pragma unroll
                    for (int rr = 0; rr < 4; ++rr) {
                        const float p = __expf(st[nt][rr] - m);
                        st[nt][rr] = p;
                        r0 += p;
                    }
                r0 += __shfl_xor(r0, 16);
                r0 += __shfl_xor(r0, 32);
                l += r0;
            } else {
                const float mn = fmaxf(m, pmax);
                const float scf = __expf(m - mn);
                m = mn;
                float r0 = 0.f;
                #pragma unroll
                for (int nt = 0; nt < 4; ++nt)
                    #pragma unroll
                    for (int rr = 0; rr < 4; ++rr) {
                        const float p = __expf(st[nt][rr] - mn);
                        st[nt][rr] = p;
                        r0 += p;
                    }
                r0 += __shfl_xor(r0, 16);
                r0 += __shfl_xor(r0, 32);
                l = l * scf + r0;
                float sc4[4];
                #pragma unroll
                for (int rr = 0; rr < 4; ++rr) sc4[rr] = __shfl(scf, g * 4 + rr);
                #pragma unroll
                for (int nt = 0; nt < 4; ++nt)
                    #pragma unroll
                    for (int rr = 0; rr < 4; ++rr)
                        o[nt][rr] *= sc4[rr];
            }

            // ---- P -> per-wave LDS: pack pairs (consecutive kv) via cvt_pk ----
            unsigned short* Pw = Psw[wave];
            #pragma unroll
            for (int nt = 0; nt < 4; ++nt) {
                const unsigned int w0 = cvt_pk_bf16(st[nt][0], st[nt][1]);
                const unsigned int w1 = cvt_pk_bf16(st[nt][2], st[nt][3]);
                const int off = (l16 * 128 + nt * 32 + g * 8) ^ ((l16 & 7) << 4);
                const unsigned long long dw = ((unsigned long long)w1 << 32) | w0;
                *(unsigned long long*)((char*)Pw + off) = dw;
            }
            // wave-private LDS: in-order per-wave DS pipe, no barrier

            __builtin_amdgcn_s_setprio(1);
            #pragma unroll
            for (int ks = 0; ks < 2; ++ks) {
                const int offp = (l16 * 128 + g * 16 + ks * 64) ^ ((l16 & 7) << 4);
                s16x8 pf = __builtin_bit_cast(s16x8, *(const u16x8*)((const char*)Pw + offp));
                #pragma unroll
                for (int nt = 0; nt < 4; ++nt) {
                    const int row = nt * 16 + l16;
                    const int off = (row * 128 + g * 16 + ks * 64) ^ ((row & 7) << 4);
                    s16x8 vf = __builtin_bit_cast(s16x8, *(const u16x8*)(Vb + off));
                    o[nt] = __builtin_amdgcn_mfma_f32_16x16x32_bf16(pf, vf, o[nt], 0, 0, 0);
                }
            }
            __builtin_amdgcn_s_setprio(0);
        }

        if (hn) {
            *(u16x8*)((char*)Ksw[cur ^ 1] + soff) = kn;
            *(u16x8*)((char*)Vsw[cur ^ 1] + soff) = vn;
        }
        __syncthreads();
        cur ^= 1;
    }

    // ---- epilogue: o rows q = g*4+rr; l lives on lane l16 = that row ----
    #pragma unroll
    for (int rr = 0; rr < 4; ++rr) {
        const float lq = __shfl(l, g * 4 + rr);
        const float inv = 1.0f / lq;
        const int q_g = qrow0 + g * 4 + rr;
        #pragma unroll
        for (int nt = 0; nt < 4; ++nt) {
            const int d = nt * 16 + l16;
            Ctx[((size_t)b * 2048 + q_g) * 1024 + h * 64 + d] = f2bf(o[nt][rr] * inv);
        }
    }
}

// =====================================================================
extern "C" void kernel_launch(void* const* d_in, const int* in_sizes, int n_in,
                              void* d_out, int out_size, void* d_ws, size_t ws_size,
                              hipStream_t stream)
{
    const float* q  = (const float*)d_in[0];
    const float* k  = (const float*)d_in[1];
    const float* v  = (const float*)d_in[2];
    const float* Wq = (const float*)d_in[4];
    const float* Wk = (const float*)d_in[5];
    const float* Wv = (const float*)d_in[6];
    const float* Wo = (const float*)d_in[7];

    const size_t NE = (size_t)4 * 16 * 2048 * 64;
    const size_t WE = (size_t)1024 * 1024;
    unsigned short* Qh = (unsigned short*)d_ws;
    unsigned short* Kh = Qh + NE;
    unsigned short* Vt = Kh + NE;
    float* outp = (float*)d_out;
    dim3 blk(256);

    if (ws_size >= 6 * NE * 2 + 4 * WE * 2) {
        unsigned short* qb  = Vt + NE;
        unsigned short* kb  = qb + NE;
        unsigned short* vb  = kb + NE;
        unsigned short* wb  = vb + NE;
        unsigned short* Ctx = qb;
        conv_kernel<<<dim3(14336), blk, 0, stream>>>(q, k, v, Wq, Wk, Wv, Wo,
                                                     qb, kb, vb, wb);
        gemm3<0><<<dim3(768), dim3(512), 0, stream>>>(
            qb, kb, vb, wb, Qh, Kh, Vt, nullptr);
        attn_kernel<<<dim3(1024), dim3(512), 0, stream>>>(Qh, Kh, Vt, Ctx);
        gemm3<1><<<dim3(256), dim3(512), 0, stream>>>(
            Ctx, nullptr, nullptr, wb + 3 * WE, nullptr, nullptr, nullptr, outp);
    } else {
        unsigned short* Ctx = Vt + NE;
        gemm_k<1, 1, 0><<<dim3(1536), blk, 0, stream>>>(
            q, k, v, Wq, Wk, Wv, Qh, Kh, Vt, nullptr);
        attn_kernel<<<dim3(1024), dim3(512), 0, stream>>>(Qh, Kh, Vt, Ctx);
        gemm_k<0, 1, 1><<<dim3(512), blk, 0, stream>>>(
            Ctx, nullptr, nullptr, Wo, nullptr, nullptr,
            nullptr, nullptr, nullptr, outp);
    }
}